// Round 7
// baseline (928.539 us; speedup 1.0000x reference)
//
#include <hip/hip_runtime.h>
#include <hip/hip_fp16.h>

// GCN 3-layer forward. R12 = R11 + full occupancy on the pulls:
//  - 1 node/thread (was 2), grid 977 blocks, __launch_bounds__(512,8)
//    -> 4 blk/CU, 32 waves/CU (R11 was 2 blk/CU, 44% occ: launch_bounds 2nd
//    arg is waves/EU, and 489-block grid gave 1.9 blk/CU)
//  - R11 lesson: pulls are L2-latency-bound (~190cy/VMEM instr at 4 waves/SIMD,
//    10% HBM, 19% VALU); double the independent chains per SIMD
//  - CSR build, phases, softbar, vectorized gathers identical
// R11: 867 us, pull1/2 182 us each, FETCH 121MB (near-compulsory).

typedef unsigned int uint;
typedef unsigned short ushort;
typedef unsigned long long ull;

#define NBMAX 1024        // max buckets (dst >> 9), 512 nodes each
#define BKN 512
#define BCAP 17408        // bucketed slab cap per bucket (mean 16384, +8 sigma)
#define SCAP 24576        // srcS slab cap (mean ~22.4k padded, +16 sigma)
#define PT_THREADS 512
#define PT_TILE 8192      // 16 edges per thread
#define NPART 8           // src partitions (src>>16): 2MB fp16 table slices
#define BAR_STRIDE 528    // uints per barrier row (root + 32 spread counters)
#define BAR_LAYER (7 * BAR_STRIDE)

// ---- init: fixed slab cursors + barrier counters ----
__global__ void k_init(uint* __restrict__ gcur, uint* __restrict__ bars) {
    int t = threadIdx.x;                 // 1024 threads, 1 block
    gcur[t] = (uint)t * BCAP;
    for (int i = t; i < 3 * BAR_LAYER; i += 1024) bars[i] = 0;
}

// ---- LDS-staged partition: edges -> bucketed (packed src | dstLocal<<19) ----
__global__ __launch_bounds__(PT_THREADS) void k_part(const int* __restrict__ src,
                                                     const int* __restrict__ dst, int E,
                                                     uint* __restrict__ gcur,
                                                     uint* __restrict__ bucketed) {
    __shared__ uint stage[PT_TILE];
    __shared__ ushort sbuck[PT_TILE];
    __shared__ uint hist[NBMAX], lofs[NBMAX], base[NBMAX];
    __shared__ uint tsum[PT_THREADS];
    int t = threadIdx.x;
    long long start = (long long)blockIdx.x * PT_TILE;
    int cnt = (int)min((long long)PT_TILE, (long long)E - start);

    hist[2 * t] = 0; hist[2 * t + 1] = 0;
    __syncthreads();
    uint myb[16], myr[16], mys[16];
#pragma unroll
    for (int k = 0; k < 16; ++k) {
        int idx = t + k * PT_THREADS;
        if (idx < cnt) {
            uint d = (uint)dst[start + idx];
            uint s = (uint)src[start + idx];
            uint b = d >> 9;
            myb[k] = b;
            mys[k] = s | ((d & 511u) << 19);
            myr[k] = atomicAdd(&hist[b], 1u);
        }
    }
    __syncthreads();
    uint h0 = hist[2 * t], h1 = hist[2 * t + 1];
    tsum[t] = h0 + h1;
    __syncthreads();
    for (int off = 1; off < PT_THREADS; off <<= 1) {
        uint x = (t >= off) ? tsum[t - off] : 0u;
        __syncthreads();
        tsum[t] += x;
        __syncthreads();
    }
    uint ex = tsum[t] - (h0 + h1);
    lofs[2 * t] = ex;
    lofs[2 * t + 1] = ex + h0;
    if (h0) base[2 * t] = atomicAdd(&gcur[2 * t], h0);
    if (h1) base[2 * t + 1] = atomicAdd(&gcur[2 * t + 1], h1);
    __syncthreads();
#pragma unroll
    for (int k = 0; k < 16; ++k) {
        int idx = t + k * PT_THREADS;
        if (idx < cnt) {
            uint pos = lofs[myb[k]] + myr[k];
            stage[pos] = mys[k];
            sbuck[pos] = (ushort)myb[k];
        }
    }
    __syncthreads();
#pragma unroll
    for (int k = 0; k < 16; ++k) {
        int idx = t + k * PT_THREADS;
        if (idx < cnt) {
            uint b = sbuck[idx];
            uint pos = base[b] + ((uint)idx - lofs[b]);
            if (pos < (uint)(b + 1) * BCAP) bucketed[pos] = stage[idx];  // ~always
        }
    }
}

// ---- per-bucket CSR: counting sort keyed (srcPart*512 + dstLocal), pad-to-4 ----
// rowp8[(p<<19)+node] = (slabStart+segStart) | (cnt<<25); pad slots = sentinel N.
__global__ __launch_bounds__(512) void k_csr(const uint* __restrict__ bucketed,
                                             const uint* __restrict__ gcur,
                                             uint* __restrict__ rowp8,
                                             float* __restrict__ dis,
                                             int* __restrict__ srcS, int N) {
    __shared__ uint c[BKN * NPART];        // counts -> cursors (reused)
    __shared__ uint tsum[512];
    __shared__ __align__(16) int stage[SCAP];
    int b = blockIdx.x, t = threadIdx.x;
    uint beg = (uint)b * BCAP;
    uint end = min(gcur[b], (uint)(b + 1) * BCAP);
    for (int i = t; i < BKN * NPART; i += 512) c[i] = 0;
    __syncthreads();
    for (uint e = beg + t; e < end; e += 512) {
        uint v = bucketed[e];
        uint key = (((v & 0x7ffffu) >> 16) << 9) | (v >> 19);
        atomicAdd(&c[key], 1u);
    }
    __syncthreads();
    // degree -> dis (before counts become cursors)
    {
        int node = (b << 9) + t;
        if (node < N) {
            uint deg = 0;
#pragma unroll
            for (int p = 0; p < NPART; ++p) deg += c[(p << 9) | t];
            dis[node] = rsqrtf((float)(deg + 1u));   // +1 self-loop
        }
    }
    // thread t owns keys 8t..8t+7 (one partition p=t>>6, 8 consecutive locals)
    uint cnt[8], pad[8], ps = 0;
#pragma unroll
    for (int i = 0; i < 8; ++i) {
        cnt[i] = c[t * 8 + i];
        pad[i] = (cnt[i] + 3u) & ~3u;
        ps += pad[i];
    }
    __syncthreads();
    tsum[t] = ps;
    __syncthreads();
    for (int off = 1; off < 512; off <<= 1) {
        uint x = (t >= off) ? tsum[t - off] : 0u;
        __syncthreads();
        tsum[t] += x;
        __syncthreads();
    }
    uint tot = tsum[511];
    uint kb = tsum[t] - ps;
    uint slab = (uint)b * SCAP;
    int p = t >> 6, local0 = (t & 63) << 3;
    uint run = kb;
#pragma unroll
    for (int i = 0; i < 8; ++i) {
        uint st = run;
        rowp8[((uint)p << 19) + (uint)((b << 9) + local0 + i)] =
            (slab + st) | (cnt[i] << 25);
        c[t * 8 + i] = st;                  // cursor, slab-relative
        for (uint q = cnt[i]; q < pad[i]; ++q) {   // sentinel pads (<=3)
            uint idx = st + q;
            if (idx < (uint)SCAP) stage[idx] = N;
            else srcS[slab + idx] = N;      // ~never (spill)
        }
        run += pad[i];
    }
    __syncthreads();
    for (uint e = beg + t; e < end; e += 512) {
        uint v = bucketed[e];
        uint s = v & 0x7ffffu;
        uint key = ((s >> 16) << 9) | (v >> 19);
        uint idx = atomicAdd(&c[key], 1u);
        if (idx < (uint)SCAP) stage[idx] = (int)s;
        else srcS[slab + idx] = (int)s;     // ~never (spill)
    }
    __syncthreads();
    uint capped = min(tot, (uint)SCAP);
    uint cap4 = capped & ~3u;
    for (uint i = t * 4; i < cap4; i += 512 * 4)
        *(int4*)(srcS + slab + i) = *(const int4*)(stage + i);
    if (t < (int)(capped & 3u)) srcS[slab + cap4 + t] = stage[cap4 + t];
}

// ---- layer-1: A'[i,0:15] = (x[i,:]@W1) * dis[i] -> fp16, A'[i,15]=0 ----
__global__ void k_lin_first(const float* __restrict__ x, const float* __restrict__ W,
                            const float* __restrict__ dis, __half* __restrict__ A, int N) {
    int i = blockIdx.x * blockDim.x + threadIdx.x;
    if (i >= N) return;
    float in[15];
#pragma unroll
    for (int j = 0; j < 15; ++j) in[j] = x[i * 15 + j];
    float di = dis[i];
#pragma unroll
    for (int o = 0; o < 15; ++o) {
        float acc = 0.f;
#pragma unroll
        for (int j = 0; j < 15; ++j) acc = fmaf(in[j], W[j * 15 + o], acc);
        A[i * 16 + o] = __float2half(acc * di);
    }
    A[i * 16 + 15] = __float2half(0.f);
}

// ---- soft global barrier: locality pacing only (no correctness dependence) ----
__device__ __forceinline__ void softbar(uint* __restrict__ bars, int phase, int nblk) {
    __syncthreads();
    if (threadIdx.x == 0) {
        uint* row = bars + phase * BAR_STRIDE;
        uint ngroups = ((uint)nblk + 31u) >> 5;
        uint g = (uint)blockIdx.x >> 5;
        uint gsz = min(32u, (uint)nblk - g * 32u);
        uint prev = atomicAdd(&row[16 + g * 16], 1u);   // spread counters, own line
        if (prev + 1u == gsz) atomicAdd(&row[0], 1u);
        int spins = 0;
        while (spins < 2000) {
            uint v = __hip_atomic_load(&row[0], __ATOMIC_RELAXED,
                                       __HIP_MEMORY_SCOPE_AGENT);
            if (v >= ngroups) break;
            __builtin_amdgcn_s_sleep(8);
            ++spins;
        }
    }
    __syncthreads();
}

template <int TW>
__device__ __forceinline__ void load_row(const __half* __restrict__ tab, int node,
                                         float (&acc)[TW]) {
    if constexpr (TW == 16) {
        int4 w0 = *(const int4*)(tab + (size_t)node * 16);
        int4 w1 = *(const int4*)(tab + (size_t)node * 16 + 8);
        const __half2* h0 = (const __half2*)&w0;
        const __half2* h1 = (const __half2*)&w1;
#pragma unroll
        for (int u = 0; u < 4; ++u) {
            float2 f0 = __half22float2(h0[u]);
            float2 f1 = __half22float2(h1[u]);
            acc[2 * u] = f0.x;
            acc[2 * u + 1] = f0.y;
            acc[8 + 2 * u] = f1.x;
            acc[8 + 2 * u + 1] = f1.y;
        }
    } else {
        int2 w = *(const int2*)(tab + (size_t)node * 4);
        const __half2* h = (const __half2*)&w;
        float2 f0 = __half22float2(h[0]);
        float2 f1 = __half22float2(h[1]);
        acc[0] = f0.x; acc[1] = f0.y; acc[2] = f1.x; acc[3] = f1.y;
    }
}

// vectorized gather: 32B rows as 2x dwordx4, 8B rows as dwordx2
template <int TW>
__device__ __forceinline__ void gather_seg(const __half* __restrict__ tab,
                                           const int* __restrict__ srcS,
                                           uint rv, float (&acc)[TW]) {
    uint cnt = rv >> 25;
    if (!cnt) return;
    uint e = rv & 0x1ffffffu;
    uint end4 = e + ((cnt + 3u) & ~3u);
    for (; e < end4; e += 4) {
        int4 s4 = *(const int4*)(srcS + e);     // 16B-aligned segment
        if constexpr (TW == 16) {
            const int4* p0 = (const int4*)(tab + (size_t)s4.x * 16);
            const int4* p1 = (const int4*)(tab + (size_t)s4.y * 16);
            const int4* p2 = (const int4*)(tab + (size_t)s4.z * 16);
            const int4* p3 = (const int4*)(tab + (size_t)s4.w * 16);
            int4 r[8];
            r[0] = p0[0]; r[1] = p1[0]; r[2] = p2[0]; r[3] = p3[0];
            r[4] = p0[1]; r[5] = p1[1]; r[6] = p2[1]; r[7] = p3[1];
#pragma unroll
            for (int q = 0; q < 8; ++q) {
                const __half2* h2 = (const __half2*)&r[q];
                int base = (q >> 2) * 8;        // r[0..3] -> lo half, r[4..7] -> hi
#pragma unroll
                for (int u = 0; u < 4; ++u) {
                    float2 f = __half22float2(h2[u]);
                    acc[base + 2 * u] += f.x;
                    acc[base + 2 * u + 1] += f.y;
                }
            }
        } else {                                // TW == 4
            int2 r0 = *(const int2*)(tab + (size_t)s4.x * 4);
            int2 r1 = *(const int2*)(tab + (size_t)s4.y * 4);
            int2 r2 = *(const int2*)(tab + (size_t)s4.z * 4);
            int2 r3 = *(const int2*)(tab + (size_t)s4.w * 4);
            const __half2* h0 = (const __half2*)&r0;
            const __half2* h1 = (const __half2*)&r1;
            const __half2* h2 = (const __half2*)&r2;
            const __half2* h3 = (const __half2*)&r3;
#pragma unroll
            for (int u = 0; u < 2; ++u) {
                float2 f0 = __half22float2(h0[u]);
                float2 f1 = __half22float2(h1[u]);
                float2 f2 = __half22float2(h2[u]);
                float2 f3 = __half22float2(h3[u]);
                acc[2 * u] += (f0.x + f1.x) + (f2.x + f3.x);
                acc[2 * u + 1] += (f0.y + f1.y) + (f2.y + f3.y);
            }
        }
    }
}

// ---- resident phased pull: 1 node/thread, 977 blocks, 4 blk/CU, 8 phases ----
// L=1: Ap->relu@W2->Bp  L=2: Bp->relu@W3->Cp  L=3: Cp->out fp32
template <int L>
__global__ __launch_bounds__(512, 8) void k_pull_res(
    const __half* __restrict__ tab, const int* __restrict__ srcS,
    const uint* __restrict__ rowp8, const float* __restrict__ dis,
    const float* __restrict__ Wm, const float* __restrict__ bias,
    void* __restrict__ outp, uint* __restrict__ bars, int nblk, int N) {
    constexpr int TW = (L == 3) ? 4 : 16;
    __shared__ float wl[240];
    int t = threadIdx.x;
    int node = (blockIdx.x << 9) + t;
    if constexpr (L == 1) {
        for (int i = t; i < 225; i += 512) wl[i] = Wm[i];
        if (t < 15) wl[225 + t] = bias[t];
    }
    if constexpr (L == 2) {
        for (int i = t; i < 60; i += 512) wl[i] = Wm[i];
        if (t < 15) wl[60 + t] = bias[t];
    }
    if constexpr (L == 3) {
        if (t < 4) wl[t] = bias[t];
    }
    __syncthreads();
    bool v = node < N;
    float a[TW];
    if (v) load_row<TW>(tab, node, a);
    uint rv = v ? rowp8[(uint)node] : 0u;      // phase-0 descriptor
    for (int p = 0; p < NPART; ++p) {
        uint nv = 0u;
        if (p < NPART - 1) {                   // prefetch next phase descriptor
            uint pb = (uint)(p + 1) << 19;
            if (v) nv = rowp8[pb + (uint)node];
        }
        if (v) gather_seg<TW>(tab, srcS, rv, a);
        if (p < NPART - 1) softbar(bars, p, nblk);
        rv = nv;
    }
    // epilogue (all-register MLP)
    if (!v) return;
    float di = dis[node];
    if constexpr (L == 3) {
        float4 o;
        o.x = a[0] * di + wl[0];
        o.y = a[1] * di + wl[1];
        o.z = a[2] * di + wl[2];
        o.w = a[3] * di + wl[3];
        *(float4*)((float*)outp + (size_t)node * 4) = o;
    } else {
        float h[15];
#pragma unroll
        for (int j = 0; j < 15; ++j) {
            float bj = (L == 1) ? wl[225 + j] : wl[60 + j];
            h[j] = fmaxf(a[j] * di + bj, 0.f);
        }
        if constexpr (L == 1) {
            float o[16];
            o[15] = 0.f;
#pragma unroll
            for (int j = 0; j < 15; ++j) {
                float s = 0.f;
#pragma unroll
                for (int k = 0; k < 15; ++k) s = fmaf(h[k], wl[k * 15 + j], s);
                o[j] = s * di;
            }
            __half2 ob[8];
#pragma unroll
            for (int j = 0; j < 8; ++j)
                ob[j] = __floats2half2_rn(o[2 * j], o[2 * j + 1]);
            *(int4*)((__half*)outp + (size_t)node * 16) = *(int4*)&ob[0];
            *(int4*)((__half*)outp + (size_t)node * 16 + 8) = *(int4*)&ob[4];
        } else {
            float o[4];
#pragma unroll
            for (int j = 0; j < 4; ++j) {
                float s = 0.f;
#pragma unroll
                for (int k = 0; k < 15; ++k) s = fmaf(h[k], wl[k * 4 + j], s);
                o[j] = s * di;
            }
            __half2 ob[2];
            ob[0] = __floats2half2_rn(o[0], o[1]);
            ob[1] = __floats2half2_rn(o[2], o[3]);
            *(float2*)((__half*)outp + (size_t)node * 4) = *(float2*)&ob[0];
        }
    }
}

extern "C" void kernel_launch(void* const* d_in, const int* in_sizes, int n_in,
                              void* d_out, int out_size, void* d_ws, size_t ws_size,
                              hipStream_t stream) {
    const float* x  = (const float*)d_in[0];
    const int*   ei = (const int*)d_in[1];
    const float* W1 = (const float*)d_in[3];
    const float* b1 = (const float*)d_in[4];
    const float* W2 = (const float*)d_in[5];
    const float* b2 = (const float*)d_in[6];
    const float* W3 = (const float*)d_in[7];
    const float* b3 = (const float*)d_in[8];
    float* out = (float*)d_out;

    const int N = in_sizes[0] / 15;
    const int E = in_sizes[1] / 2;
    const int* src = ei;
    const int* dst = ei + E;
    const int NBr = (N + BKN - 1) / BKN;   // live buckets (977)
    const int PB  = NBr;                   // pull blocks = buckets (977 <= 1024)

    char* ws = (char*)d_ws;
    auto align = [](size_t v) { return (v + 255) & ~(size_t)255; };
    size_t off = 0;
    uint* rowp8 = (uint*)(ws + off); off += align((size_t)NPART * (1u << 19) * 4);
    float* dis  = (float*)(ws + off); off += align((size_t)N * 4);
    uint* gcur  = (uint*)(ws + off); off += align((size_t)NBMAX * 4);
    uint* bars  = (uint*)(ws + off); off += align((size_t)3 * BAR_LAYER * 4);
    int*  srcS  = (int*)(ws + off);  off += align((size_t)NBMAX * SCAP * 4);
    // slabY: bucketed (71MB) dead after k_csr, overlaid by B'(fp16)+C'(fp16)
    char* slabY = ws + off;
    uint*   bucketed = (uint*)slabY;
    __half* Bp = (__half*)slabY;
    __half* Cp = (__half*)(slabY + align((size_t)(N + 1) * 16 * 2));
    off += align((size_t)NBMAX * BCAP * 4);
    __half* Ap = (__half*)(ws + off);  // (N+1) x 16 fp16

    const int nTiles = (E + PT_TILE - 1) / PT_TILE;
    const int nbN = (N + 255) / 256;

    // CSR build (partition-major rows, fixed slabs)
    k_init<<<1, 1024, 0, stream>>>(gcur, bars);
    k_part<<<nTiles, PT_THREADS, 0, stream>>>(src, dst, E, gcur, bucketed);
    k_csr<<<NBr, 512, 0, stream>>>(bucketed, gcur, rowp8, dis, srcS, N);
    // bucketed dead -> slabY becomes B'/C'

    k_lin_first<<<nbN, 256, 0, stream>>>(x, W1, dis, Ap, N);
    // sentinel zero-rows (row N) for pad gathers
    hipMemsetAsync(Ap + (size_t)N * 16, 0, 16 * 2, stream);
    hipMemsetAsync(Bp + (size_t)N * 16, 0, 16 * 2, stream);
    hipMemsetAsync(Cp + (size_t)N * 4, 0, 4 * 2, stream);

    k_pull_res<1><<<PB, 512, 0, stream>>>(Ap, srcS, rowp8, dis, W2, b1, Bp,
                                          bars + 0 * BAR_LAYER, PB, N);
    k_pull_res<2><<<PB, 512, 0, stream>>>(Bp, srcS, rowp8, dis, W3, b2, Cp,
                                          bars + 1 * BAR_LAYER, PB, N);
    k_pull_res<3><<<PB, 512, 0, stream>>>(Cp, srcS, rowp8, dis, nullptr, b3, out,
                                          bars + 2 * BAR_LAYER, PB, N);
}

// Round 8
// 926.733 us; speedup vs baseline: 1.0019x; 1.0019x over previous
//
#include <hip/hip_runtime.h>
#include <hip/hip_fp16.h>

// GCN 3-layer forward. R13 = R12 + lane-paired row gathers (probe halving):
//  - pull1/2: adjacent lanes load the two 16B halves of one 32B row in the
//    SAME instruction -> 1 coalesced L1 line-probe per row (R12: 2 probes).
//    Thread owns half-rows of 2 nodes (acc 8+8 fp32); epilogue exchanges
//    halves via padded LDS (stride 17) then register MLP.
//  - R12 lesson: occupancy 44->88% changed nothing -> pulls are bound by
//    per-CU TCP line-probe rate (~2.4cy/request), not latency hiding.
//  - CSR build, phases, softbar, pull3 identical to R12.
// R12: 928 us, pull1/2 196 us each, FETCH 123MB (near-compulsory).

typedef unsigned int uint;
typedef unsigned short ushort;
typedef unsigned long long ull;

#define NBMAX 1024        // max buckets (dst >> 9), 512 nodes each
#define BKN 512
#define BCAP 17408        // bucketed slab cap per bucket (mean 16384, +8 sigma)
#define SCAP 24576        // srcS slab cap (mean ~22.4k padded, +16 sigma)
#define PT_THREADS 512
#define PT_TILE 8192      // 16 edges per thread
#define NPART 8           // src partitions (src>>16): 2MB fp16 table slices
#define BAR_STRIDE 528    // uints per barrier row (root + 32 spread counters)
#define BAR_LAYER (7 * BAR_STRIDE)

// ---- init: fixed slab cursors + barrier counters ----
__global__ void k_init(uint* __restrict__ gcur, uint* __restrict__ bars) {
    int t = threadIdx.x;                 // 1024 threads, 1 block
    gcur[t] = (uint)t * BCAP;
    for (int i = t; i < 3 * BAR_LAYER; i += 1024) bars[i] = 0;
}

// ---- LDS-staged partition: edges -> bucketed (packed src | dstLocal<<19) ----
__global__ __launch_bounds__(PT_THREADS) void k_part(const int* __restrict__ src,
                                                     const int* __restrict__ dst, int E,
                                                     uint* __restrict__ gcur,
                                                     uint* __restrict__ bucketed) {
    __shared__ uint stage[PT_TILE];
    __shared__ ushort sbuck[PT_TILE];
    __shared__ uint hist[NBMAX], lofs[NBMAX], base[NBMAX];
    __shared__ uint tsum[PT_THREADS];
    int t = threadIdx.x;
    long long start = (long long)blockIdx.x * PT_TILE;
    int cnt = (int)min((long long)PT_TILE, (long long)E - start);

    hist[2 * t] = 0; hist[2 * t + 1] = 0;
    __syncthreads();
    uint myb[16], myr[16], mys[16];
#pragma unroll
    for (int k = 0; k < 16; ++k) {
        int idx = t + k * PT_THREADS;
        if (idx < cnt) {
            uint d = (uint)dst[start + idx];
            uint s = (uint)src[start + idx];
            uint b = d >> 9;
            myb[k] = b;
            mys[k] = s | ((d & 511u) << 19);
            myr[k] = atomicAdd(&hist[b], 1u);
        }
    }
    __syncthreads();
    uint h0 = hist[2 * t], h1 = hist[2 * t + 1];
    tsum[t] = h0 + h1;
    __syncthreads();
    for (int off = 1; off < PT_THREADS; off <<= 1) {
        uint x = (t >= off) ? tsum[t - off] : 0u;
        __syncthreads();
        tsum[t] += x;
        __syncthreads();
    }
    uint ex = tsum[t] - (h0 + h1);
    lofs[2 * t] = ex;
    lofs[2 * t + 1] = ex + h0;
    if (h0) base[2 * t] = atomicAdd(&gcur[2 * t], h0);
    if (h1) base[2 * t + 1] = atomicAdd(&gcur[2 * t + 1], h1);
    __syncthreads();
#pragma unroll
    for (int k = 0; k < 16; ++k) {
        int idx = t + k * PT_THREADS;
        if (idx < cnt) {
            uint pos = lofs[myb[k]] + myr[k];
            stage[pos] = mys[k];
            sbuck[pos] = (ushort)myb[k];
        }
    }
    __syncthreads();
#pragma unroll
    for (int k = 0; k < 16; ++k) {
        int idx = t + k * PT_THREADS;
        if (idx < cnt) {
            uint b = sbuck[idx];
            uint pos = base[b] + ((uint)idx - lofs[b]);
            if (pos < (uint)(b + 1) * BCAP) bucketed[pos] = stage[idx];  // ~always
        }
    }
}

// ---- per-bucket CSR: counting sort keyed (srcPart*512 + dstLocal), pad-to-4 ----
// rowp8[(p<<19)+node] = (slabStart+segStart) | (cnt<<25); pad slots = sentinel N.
__global__ __launch_bounds__(512) void k_csr(const uint* __restrict__ bucketed,
                                             const uint* __restrict__ gcur,
                                             uint* __restrict__ rowp8,
                                             float* __restrict__ dis,
                                             int* __restrict__ srcS, int N) {
    __shared__ uint c[BKN * NPART];        // counts -> cursors (reused)
    __shared__ uint tsum[512];
    __shared__ __align__(16) int stage[SCAP];
    int b = blockIdx.x, t = threadIdx.x;
    uint beg = (uint)b * BCAP;
    uint end = min(gcur[b], (uint)(b + 1) * BCAP);
    for (int i = t; i < BKN * NPART; i += 512) c[i] = 0;
    __syncthreads();
    for (uint e = beg + t; e < end; e += 512) {
        uint v = bucketed[e];
        uint key = (((v & 0x7ffffu) >> 16) << 9) | (v >> 19);
        atomicAdd(&c[key], 1u);
    }
    __syncthreads();
    // degree -> dis (before counts become cursors)
    {
        int node = (b << 9) + t;
        if (node < N) {
            uint deg = 0;
#pragma unroll
            for (int p = 0; p < NPART; ++p) deg += c[(p << 9) | t];
            dis[node] = rsqrtf((float)(deg + 1u));   // +1 self-loop
        }
    }
    // thread t owns keys 8t..8t+7 (one partition p=t>>6, 8 consecutive locals)
    uint cnt[8], pad[8], ps = 0;
#pragma unroll
    for (int i = 0; i < 8; ++i) {
        cnt[i] = c[t * 8 + i];
        pad[i] = (cnt[i] + 3u) & ~3u;
        ps += pad[i];
    }
    __syncthreads();
    tsum[t] = ps;
    __syncthreads();
    for (int off = 1; off < 512; off <<= 1) {
        uint x = (t >= off) ? tsum[t - off] : 0u;
        __syncthreads();
        tsum[t] += x;
        __syncthreads();
    }
    uint tot = tsum[511];
    uint kb = tsum[t] - ps;
    uint slab = (uint)b * SCAP;
    int p = t >> 6, local0 = (t & 63) << 3;
    uint run = kb;
#pragma unroll
    for (int i = 0; i < 8; ++i) {
        uint st = run;
        rowp8[((uint)p << 19) + (uint)((b << 9) + local0 + i)] =
            (slab + st) | (cnt[i] << 25);
        c[t * 8 + i] = st;                  // cursor, slab-relative
        for (uint q = cnt[i]; q < pad[i]; ++q) {   // sentinel pads (<=3)
            uint idx = st + q;
            if (idx < (uint)SCAP) stage[idx] = N;
            else srcS[slab + idx] = N;      // ~never (spill)
        }
        run += pad[i];
    }
    __syncthreads();
    for (uint e = beg + t; e < end; e += 512) {
        uint v = bucketed[e];
        uint s = v & 0x7ffffu;
        uint key = ((s >> 16) << 9) | (v >> 19);
        uint idx = atomicAdd(&c[key], 1u);
        if (idx < (uint)SCAP) stage[idx] = (int)s;
        else srcS[slab + idx] = (int)s;     // ~never (spill)
    }
    __syncthreads();
    uint capped = min(tot, (uint)SCAP);
    uint cap4 = capped & ~3u;
    for (uint i = t * 4; i < cap4; i += 512 * 4)
        *(int4*)(srcS + slab + i) = *(const int4*)(stage + i);
    if (t < (int)(capped & 3u)) srcS[slab + cap4 + t] = stage[cap4 + t];
}

// ---- layer-1: A'[i,0:15] = (x[i,:]@W1) * dis[i] -> fp16, A'[i,15]=0 ----
__global__ void k_lin_first(const float* __restrict__ x, const float* __restrict__ W,
                            const float* __restrict__ dis, __half* __restrict__ A, int N) {
    int i = blockIdx.x * blockDim.x + threadIdx.x;
    if (i >= N) return;
    float in[15];
#pragma unroll
    for (int j = 0; j < 15; ++j) in[j] = x[i * 15 + j];
    float di = dis[i];
#pragma unroll
    for (int o = 0; o < 15; ++o) {
        float acc = 0.f;
#pragma unroll
        for (int j = 0; j < 15; ++j) acc = fmaf(in[j], W[j * 15 + o], acc);
        A[i * 16 + o] = __float2half(acc * di);
    }
    A[i * 16 + 15] = __float2half(0.f);
}

// ---- soft global barrier: locality pacing only (no correctness dependence) ----
__device__ __forceinline__ void softbar(uint* __restrict__ bars, int phase, int nblk) {
    __syncthreads();
    if (threadIdx.x == 0) {
        uint* row = bars + phase * BAR_STRIDE;
        uint ngroups = ((uint)nblk + 31u) >> 5;
        uint g = (uint)blockIdx.x >> 5;
        uint gsz = min(32u, (uint)nblk - g * 32u);
        uint prev = atomicAdd(&row[16 + g * 16], 1u);   // spread counters, own line
        if (prev + 1u == gsz) atomicAdd(&row[0], 1u);
        int spins = 0;
        while (spins < 2000) {
            uint v = __hip_atomic_load(&row[0], __ATOMIC_RELAXED,
                                       __HIP_MEMORY_SCOPE_AGENT);
            if (v >= ngroups) break;
            __builtin_amdgcn_s_sleep(8);
            ++spins;
        }
    }
    __syncthreads();
}

// half-row self load: 16B (8 halves) at half-index j2
__device__ __forceinline__ void load_half(const __half* __restrict__ tab, int node,
                                          int j2, float (&acc)[8]) {
    int4 w = *(const int4*)(tab + (size_t)node * 16 + j2 * 8);
    const __half2* h = (const __half2*)&w;
#pragma unroll
    for (int u = 0; u < 4; ++u) {
        float2 f = __half22float2(h[u]);
        acc[2 * u] = f.x;
        acc[2 * u + 1] = f.y;
    }
}

// lane-paired gather: this lane accumulates half j2 (16B) of each row;
// partner lane (same pair) covers the other half -> 1 line-probe per row.
__device__ __forceinline__ void gather_half(const __half* __restrict__ tab,
                                            const int* __restrict__ srcS,
                                            uint rv, int j2, float (&acc)[8]) {
    uint cnt = rv >> 25;
    if (!cnt) return;
    uint e = rv & 0x1ffffffu;
    uint end4 = e + ((cnt + 3u) & ~3u);
    for (; e < end4; e += 4) {
        int4 s4 = *(const int4*)(srcS + e);     // same addr across pair: broadcast
        int4 r0 = *(const int4*)(tab + (size_t)s4.x * 16 + j2 * 8);
        int4 r1 = *(const int4*)(tab + (size_t)s4.y * 16 + j2 * 8);
        int4 r2 = *(const int4*)(tab + (size_t)s4.z * 16 + j2 * 8);
        int4 r3 = *(const int4*)(tab + (size_t)s4.w * 16 + j2 * 8);
        const __half2* h0 = (const __half2*)&r0;
        const __half2* h1 = (const __half2*)&r1;
        const __half2* h2 = (const __half2*)&r2;
        const __half2* h3 = (const __half2*)&r3;
#pragma unroll
        for (int u = 0; u < 4; ++u) {
            float2 f0 = __half22float2(h0[u]);
            float2 f1 = __half22float2(h1[u]);
            float2 f2 = __half22float2(h2[u]);
            float2 f3 = __half22float2(h3[u]);
            acc[2 * u] += (f0.x + f1.x) + (f2.x + f3.x);
            acc[2 * u + 1] += (f0.y + f1.y) + (f2.y + f3.y);
        }
    }
}

// full-row gather for 8B rows (pull3)
__device__ __forceinline__ void gather_row4(const __half* __restrict__ tab,
                                            const int* __restrict__ srcS,
                                            uint rv, float (&acc)[4]) {
    uint cnt = rv >> 25;
    if (!cnt) return;
    uint e = rv & 0x1ffffffu;
    uint end4 = e + ((cnt + 3u) & ~3u);
    for (; e < end4; e += 4) {
        int4 s4 = *(const int4*)(srcS + e);
        int2 r0 = *(const int2*)(tab + (size_t)s4.x * 4);
        int2 r1 = *(const int2*)(tab + (size_t)s4.y * 4);
        int2 r2 = *(const int2*)(tab + (size_t)s4.z * 4);
        int2 r3 = *(const int2*)(tab + (size_t)s4.w * 4);
        const __half2* h0 = (const __half2*)&r0;
        const __half2* h1 = (const __half2*)&r1;
        const __half2* h2 = (const __half2*)&r2;
        const __half2* h3 = (const __half2*)&r3;
#pragma unroll
        for (int u = 0; u < 2; ++u) {
            float2 f0 = __half22float2(h0[u]);
            float2 f1 = __half22float2(h1[u]);
            float2 f2 = __half22float2(h2[u]);
            float2 f3 = __half22float2(h3[u]);
            acc[2 * u] += (f0.x + f1.x) + (f2.x + f3.x);
            acc[2 * u + 1] += (f0.y + f1.y) + (f2.y + f3.y);
        }
    }
}

// ---- resident phased pull (lane-paired), 977 blocks, 4 blk/CU, 8 phases ----
// L=1: Ap->relu@W2->Bp  L=2: Bp->relu@W3->Cp  L=3: Cp->out fp32 (unpaired)
template <int L>
__global__ __launch_bounds__(512, 8) void k_pull_res(
    const __half* __restrict__ tab, const int* __restrict__ srcS,
    const uint* __restrict__ rowp8, const float* __restrict__ dis,
    const float* __restrict__ Wm, const float* __restrict__ bias,
    void* __restrict__ outp, uint* __restrict__ bars, int nblk, int N) {
    int t = threadIdx.x;
    if constexpr (L == 3) {
        __shared__ float wl[4];
        int node = (blockIdx.x << 9) + t;
        if (t < 4) wl[t] = bias[t];
        __syncthreads();
        bool v = node < N;
        float a[4];
        if (v) {
            int2 w = *(const int2*)(tab + (size_t)node * 4);
            const __half2* h = (const __half2*)&w;
            float2 f0 = __half22float2(h[0]);
            float2 f1 = __half22float2(h[1]);
            a[0] = f0.x; a[1] = f0.y; a[2] = f1.x; a[3] = f1.y;
        }
        uint rv = v ? rowp8[(uint)node] : 0u;
        for (int p = 0; p < NPART; ++p) {
            uint nv = 0u;
            if (p < NPART - 1) {
                uint pb = (uint)(p + 1) << 19;
                if (v) nv = rowp8[pb + (uint)node];
            }
            if (v) gather_row4(tab, srcS, rv, a);
            if (p < NPART - 1) softbar(bars, p, nblk);
            rv = nv;
        }
        if (!v) return;
        float di = dis[node];
        float4 o;
        o.x = a[0] * di + wl[0];
        o.y = a[1] * di + wl[1];
        o.z = a[2] * di + wl[2];
        o.w = a[3] * di + wl[3];
        *(float4*)((float*)outp + (size_t)node * 4) = o;
    } else {
        __shared__ float wl[240];
        __shared__ float sh[512 * 17];
        int pr = t >> 1, j2 = t & 1;
        int base = blockIdx.x << 9;
        int nA = base + pr, nB = base + 256 + pr;
        if constexpr (L == 1) {
            for (int i = t; i < 225; i += 512) wl[i] = Wm[i];
            if (t < 15) wl[225 + t] = bias[t];
        } else {
            for (int i = t; i < 60; i += 512) wl[i] = Wm[i];
            if (t < 15) wl[60 + t] = bias[t];
        }
        __syncthreads();
        bool vA = nA < N, vB = nB < N;
        float aA[8], aB[8];
        if (vA) load_half(tab, nA, j2, aA);
        if (vB) load_half(tab, nB, j2, aB);
        uint rvA = vA ? rowp8[(uint)nA] : 0u;
        uint rvB = vB ? rowp8[(uint)nB] : 0u;
        for (int p = 0; p < NPART; ++p) {
            uint nvA = 0u, nvB = 0u;
            if (p < NPART - 1) {               // prefetch next phase descriptors
                uint pb = (uint)(p + 1) << 19;
                if (vA) nvA = rowp8[pb + (uint)nA];
                if (vB) nvB = rowp8[pb + (uint)nB];
            }
            if (vA) gather_half(tab, srcS, rvA, j2, aA);
            if (vB) gather_half(tab, srcS, rvB, j2, aB);
            if (p < NPART - 1) softbar(bars, p, nblk);
            rvA = nvA; rvB = nvB;
        }
        // exchange halves via LDS (stride 17: 2-way bank alias = free)
        if (vA) {
#pragma unroll
            for (int u = 0; u < 8; ++u) sh[pr * 17 + j2 * 8 + u] = aA[u];
        }
        if (vB) {
#pragma unroll
            for (int u = 0; u < 8; ++u) sh[(256 + pr) * 17 + j2 * 8 + u] = aB[u];
        }
        __syncthreads();
        int node = base + t;
        if (node >= N) return;
        float di = dis[node];
        float h[15];
#pragma unroll
        for (int j = 0; j < 15; ++j) {
            float bj = (L == 1) ? wl[225 + j] : wl[60 + j];
            h[j] = fmaxf(sh[t * 17 + j] * di + bj, 0.f);
        }
        if constexpr (L == 1) {
            float o[16];
            o[15] = 0.f;
#pragma unroll
            for (int j = 0; j < 15; ++j) {
                float s = 0.f;
#pragma unroll
                for (int k = 0; k < 15; ++k) s = fmaf(h[k], wl[k * 15 + j], s);
                o[j] = s * di;
            }
            __half2 ob[8];
#pragma unroll
            for (int j = 0; j < 8; ++j)
                ob[j] = __floats2half2_rn(o[2 * j], o[2 * j + 1]);
            *(int4*)((__half*)outp + (size_t)node * 16) = *(int4*)&ob[0];
            *(int4*)((__half*)outp + (size_t)node * 16 + 8) = *(int4*)&ob[4];
        } else {
            float o[4];
#pragma unroll
            for (int j = 0; j < 4; ++j) {
                float s = 0.f;
#pragma unroll
                for (int k = 0; k < 15; ++k) s = fmaf(h[k], wl[k * 4 + j], s);
                o[j] = s * di;
            }
            __half2 ob[2];
            ob[0] = __floats2half2_rn(o[0], o[1]);
            ob[1] = __floats2half2_rn(o[2], o[3]);
            *(float2*)((__half*)outp + (size_t)node * 4) = *(float2*)&ob[0];
        }
    }
}

extern "C" void kernel_launch(void* const* d_in, const int* in_sizes, int n_in,
                              void* d_out, int out_size, void* d_ws, size_t ws_size,
                              hipStream_t stream) {
    const float* x  = (const float*)d_in[0];
    const int*   ei = (const int*)d_in[1];
    const float* W1 = (const float*)d_in[3];
    const float* b1 = (const float*)d_in[4];
    const float* W2 = (const float*)d_in[5];
    const float* b2 = (const float*)d_in[6];
    const float* W3 = (const float*)d_in[7];
    const float* b3 = (const float*)d_in[8];
    float* out = (float*)d_out;

    const int N = in_sizes[0] / 15;
    const int E = in_sizes[1] / 2;
    const int* src = ei;
    const int* dst = ei + E;
    const int NBr = (N + BKN - 1) / BKN;   // live buckets (977)
    const int PB  = NBr;                   // pull blocks = buckets (977 <= 1024)

    char* ws = (char*)d_ws;
    auto align = [](size_t v) { return (v + 255) & ~(size_t)255; };
    size_t off = 0;
    uint* rowp8 = (uint*)(ws + off); off += align((size_t)NPART * (1u << 19) * 4);
    float* dis  = (float*)(ws + off); off += align((size_t)N * 4);
    uint* gcur  = (uint*)(ws + off); off += align((size_t)NBMAX * 4);
    uint* bars  = (uint*)(ws + off); off += align((size_t)3 * BAR_LAYER * 4);
    int*  srcS  = (int*)(ws + off);  off += align((size_t)NBMAX * SCAP * 4);
    // slabY: bucketed (71MB) dead after k_csr, overlaid by B'(fp16)+C'(fp16)
    char* slabY = ws + off;
    uint*   bucketed = (uint*)slabY;
    __half* Bp = (__half*)slabY;
    __half* Cp = (__half*)(slabY + align((size_t)(N + 1) * 16 * 2));
    off += align((size_t)NBMAX * BCAP * 4);
    __half* Ap = (__half*)(ws + off);  // (N+1) x 16 fp16

    const int nTiles = (E + PT_TILE - 1) / PT_TILE;
    const int nbN = (N + 255) / 256;

    // CSR build (partition-major rows, fixed slabs)
    k_init<<<1, 1024, 0, stream>>>(gcur, bars);
    k_part<<<nTiles, PT_THREADS, 0, stream>>>(src, dst, E, gcur, bucketed);
    k_csr<<<NBr, 512, 0, stream>>>(bucketed, gcur, rowp8, dis, srcS, N);
    // bucketed dead -> slabY becomes B'/C'

    k_lin_first<<<nbN, 256, 0, stream>>>(x, W1, dis, Ap, N);
    // sentinel zero-rows (row N) for pad gathers
    hipMemsetAsync(Ap + (size_t)N * 16, 0, 16 * 2, stream);
    hipMemsetAsync(Bp + (size_t)N * 16, 0, 16 * 2, stream);
    hipMemsetAsync(Cp + (size_t)N * 4, 0, 4 * 2, stream);

    k_pull_res<1><<<PB, 512, 0, stream>>>(Ap, srcS, rowp8, dis, W2, b1, Bp,
                                          bars + 0 * BAR_LAYER, PB, N);
    k_pull_res<2><<<PB, 512, 0, stream>>>(Bp, srcS, rowp8, dis, W3, b2, Cp,
                                          bars + 1 * BAR_LAYER, PB, N);
    k_pull_res<3><<<PB, 512, 0, stream>>>(Cp, srcS, rowp8, dis, nullptr, b3, out,
                                          bars + 2 * BAR_LAYER, PB, N);
}

// Round 9
// 855.618 us; speedup vs baseline: 1.0852x; 1.0831x over previous
//
#include <hip/hip_runtime.h>
#include <hip/hip_fp16.h>

// GCN 3-layer forward. R14 = revert pulls to R11 (best: 867us, pulls 183us)
// + k_csr single-pass: bucketed entries cached in registers (34/thread,
// fully unrolled -> VGPRs) between histogram and fill passes, eliminating
// the second 64MB stream.
// Pull model (R11-R13 over-determined): ~6.8 cy per distinct line-touch per
// CU, invariant to occupancy/vectorization/pairing -> pulls are at floor.
// Remaining budget: CSR chain ~250-350us, pull3 ~110, lin ~25.

typedef unsigned int uint;
typedef unsigned short ushort;
typedef unsigned long long ull;

#define NBMAX 1024        // max buckets (dst >> 9), 512 nodes each
#define BKN 512
#define BCAP 17408        // bucketed slab cap per bucket (mean 16384, +8 sigma)
#define EPT 34            // bucketed entries per k_csr thread (BCAP/512)
#define SCAP 24576        // srcS slab cap (mean ~22.4k padded, +16 sigma)
#define PT_THREADS 512
#define PT_TILE 8192      // 16 edges per thread
#define NPART 8           // src partitions (src>>16): 2MB fp16 table slices
#define BAR_STRIDE 528    // uints per barrier row (root + 32 spread counters)
#define BAR_LAYER (7 * BAR_STRIDE)

// ---- init: fixed slab cursors + barrier counters ----
__global__ void k_init(uint* __restrict__ gcur, uint* __restrict__ bars) {
    int t = threadIdx.x;                 // 1024 threads, 1 block
    gcur[t] = (uint)t * BCAP;
    for (int i = t; i < 3 * BAR_LAYER; i += 1024) bars[i] = 0;
}

// ---- LDS-staged partition: edges -> bucketed (packed src | dstLocal<<19) ----
__global__ __launch_bounds__(PT_THREADS) void k_part(const int* __restrict__ src,
                                                     const int* __restrict__ dst, int E,
                                                     uint* __restrict__ gcur,
                                                     uint* __restrict__ bucketed) {
    __shared__ uint stage[PT_TILE];
    __shared__ ushort sbuck[PT_TILE];
    __shared__ uint hist[NBMAX], lofs[NBMAX], base[NBMAX];
    __shared__ uint tsum[PT_THREADS];
    int t = threadIdx.x;
    long long start = (long long)blockIdx.x * PT_TILE;
    int cnt = (int)min((long long)PT_TILE, (long long)E - start);

    hist[2 * t] = 0; hist[2 * t + 1] = 0;
    __syncthreads();
    uint myb[16], myr[16], mys[16];
#pragma unroll
    for (int k = 0; k < 16; ++k) {
        int idx = t + k * PT_THREADS;
        if (idx < cnt) {
            uint d = (uint)dst[start + idx];
            uint s = (uint)src[start + idx];
            uint b = d >> 9;
            myb[k] = b;
            mys[k] = s | ((d & 511u) << 19);
            myr[k] = atomicAdd(&hist[b], 1u);
        }
    }
    __syncthreads();
    uint h0 = hist[2 * t], h1 = hist[2 * t + 1];
    tsum[t] = h0 + h1;
    __syncthreads();
    for (int off = 1; off < PT_THREADS; off <<= 1) {
        uint x = (t >= off) ? tsum[t - off] : 0u;
        __syncthreads();
        tsum[t] += x;
        __syncthreads();
    }
    uint ex = tsum[t] - (h0 + h1);
    lofs[2 * t] = ex;
    lofs[2 * t + 1] = ex + h0;
    if (h0) base[2 * t] = atomicAdd(&gcur[2 * t], h0);
    if (h1) base[2 * t + 1] = atomicAdd(&gcur[2 * t + 1], h1);
    __syncthreads();
#pragma unroll
    for (int k = 0; k < 16; ++k) {
        int idx = t + k * PT_THREADS;
        if (idx < cnt) {
            uint pos = lofs[myb[k]] + myr[k];
            stage[pos] = mys[k];
            sbuck[pos] = (ushort)myb[k];
        }
    }
    __syncthreads();
#pragma unroll
    for (int k = 0; k < 16; ++k) {
        int idx = t + k * PT_THREADS;
        if (idx < cnt) {
            uint b = sbuck[idx];
            uint pos = base[b] + ((uint)idx - lofs[b]);
            if (pos < (uint)(b + 1) * BCAP) bucketed[pos] = stage[idx];  // ~always
        }
    }
}

// ---- per-bucket CSR: counting sort keyed (srcPart*512 + dstLocal), pad-to-4 ----
// rowp8[(p<<19)+node] = (slabStart+segStart) | (cnt<<25); pad slots = sentinel N.
// R14: bucketed read ONCE; entries live in registers across the two passes.
__global__ __launch_bounds__(512) void k_csr(const uint* __restrict__ bucketed,
                                             const uint* __restrict__ gcur,
                                             uint* __restrict__ rowp8,
                                             float* __restrict__ dis,
                                             int* __restrict__ srcS, int N) {
    __shared__ uint c[BKN * NPART];        // counts -> cursors (reused)
    __shared__ uint tsum[512];
    __shared__ __align__(16) int stage[SCAP];
    int b = blockIdx.x, t = threadIdx.x;
    uint beg = (uint)b * BCAP;
    uint end = min(gcur[b], (uint)(b + 1) * BCAP);
    for (int i = t; i < BKN * NPART; i += 512) c[i] = 0;
    __syncthreads();
    uint reg[EPT];                         // static-indexed (full unroll) -> VGPRs
#pragma unroll
    for (int i = 0; i < EPT; ++i) {
        uint e = beg + (uint)t + (uint)i * 512u;
        bool ok = e < end;
        uint v = ok ? bucketed[e] : 0u;
        reg[i] = ok ? v : 0xffffffffu;     // sentinel = skip
        if (ok) {
            uint key = (((v & 0x7ffffu) >> 16) << 9) | (v >> 19);
            atomicAdd(&c[key], 1u);
        }
    }
    __syncthreads();
    // degree -> dis (before counts become cursors)
    {
        int node = (b << 9) + t;
        if (node < N) {
            uint deg = 0;
#pragma unroll
            for (int p = 0; p < NPART; ++p) deg += c[(p << 9) | t];
            dis[node] = rsqrtf((float)(deg + 1u));   // +1 self-loop
        }
    }
    // thread t owns keys 8t..8t+7 (one partition p=t>>6, 8 consecutive locals)
    uint cnt[8], pad[8], ps = 0;
#pragma unroll
    for (int i = 0; i < 8; ++i) {
        cnt[i] = c[t * 8 + i];
        pad[i] = (cnt[i] + 3u) & ~3u;
        ps += pad[i];
    }
    __syncthreads();
    tsum[t] = ps;
    __syncthreads();
    for (int off = 1; off < 512; off <<= 1) {
        uint x = (t >= off) ? tsum[t - off] : 0u;
        __syncthreads();
        tsum[t] += x;
        __syncthreads();
    }
    uint tot = tsum[511];
    uint kb = tsum[t] - ps;
    uint slab = (uint)b * SCAP;
    int p = t >> 6, local0 = (t & 63) << 3;
    uint run = kb;
#pragma unroll
    for (int i = 0; i < 8; ++i) {
        uint st = run;
        rowp8[((uint)p << 19) + (uint)((b << 9) + local0 + i)] =
            (slab + st) | (cnt[i] << 25);
        c[t * 8 + i] = st;                  // cursor, slab-relative
        for (uint q = cnt[i]; q < pad[i]; ++q) {   // sentinel pads (<=3)
            uint idx = st + q;
            if (idx < (uint)SCAP) stage[idx] = N;
            else srcS[slab + idx] = N;      // ~never (spill)
        }
        run += pad[i];
    }
    __syncthreads();
#pragma unroll
    for (int i = 0; i < EPT; ++i) {
        uint v = reg[i];
        if (v != 0xffffffffu) {
            uint s = v & 0x7ffffu;
            uint key = ((s >> 16) << 9) | (v >> 19);
            uint idx = atomicAdd(&c[key], 1u);
            if (idx < (uint)SCAP) stage[idx] = (int)s;
            else srcS[slab + idx] = (int)s; // ~never (spill)
        }
    }
    __syncthreads();
    uint capped = min(tot, (uint)SCAP);
    uint cap4 = capped & ~3u;
    for (uint i = t * 4; i < cap4; i += 512 * 4)
        *(int4*)(srcS + slab + i) = *(const int4*)(stage + i);
    if (t < (int)(capped & 3u)) srcS[slab + cap4 + t] = stage[cap4 + t];
}

// ---- layer-1: A'[i,0:15] = (x[i,:]@W1) * dis[i] -> fp16, A'[i,15]=0 ----
__global__ void k_lin_first(const float* __restrict__ x, const float* __restrict__ W,
                            const float* __restrict__ dis, __half* __restrict__ A, int N) {
    int i = blockIdx.x * blockDim.x + threadIdx.x;
    if (i >= N) return;
    float in[15];
#pragma unroll
    for (int j = 0; j < 15; ++j) in[j] = x[i * 15 + j];
    float di = dis[i];
#pragma unroll
    for (int o = 0; o < 15; ++o) {
        float acc = 0.f;
#pragma unroll
        for (int j = 0; j < 15; ++j) acc = fmaf(in[j], W[j * 15 + o], acc);
        A[i * 16 + o] = __float2half(acc * di);
    }
    A[i * 16 + 15] = __float2half(0.f);
}

// ---- soft global barrier: locality pacing only (no correctness dependence) ----
__device__ __forceinline__ void softbar(uint* __restrict__ bars, int phase, int nblk) {
    __syncthreads();
    if (threadIdx.x == 0) {
        uint* row = bars + phase * BAR_STRIDE;
        uint ngroups = ((uint)nblk + 31u) >> 5;
        uint g = (uint)blockIdx.x >> 5;
        uint gsz = min(32u, (uint)nblk - g * 32u);
        uint prev = atomicAdd(&row[16 + g * 16], 1u);   // spread counters, own line
        if (prev + 1u == gsz) atomicAdd(&row[0], 1u);
        int spins = 0;
        while (spins < 2000) {
            uint v = __hip_atomic_load(&row[0], __ATOMIC_RELAXED,
                                       __HIP_MEMORY_SCOPE_AGENT);
            if (v >= ngroups) break;
            __builtin_amdgcn_s_sleep(8);
            ++spins;
        }
    }
    __syncthreads();
}

template <int TW>
__device__ __forceinline__ void load_row(const __half* __restrict__ tab, int node,
                                         float (&acc)[TW]) {
    if constexpr (TW == 16) {
        int4 w0 = *(const int4*)(tab + (size_t)node * 16);
        int4 w1 = *(const int4*)(tab + (size_t)node * 16 + 8);
        const __half2* h0 = (const __half2*)&w0;
        const __half2* h1 = (const __half2*)&w1;
#pragma unroll
        for (int u = 0; u < 4; ++u) {
            float2 f0 = __half22float2(h0[u]);
            float2 f1 = __half22float2(h1[u]);
            acc[2 * u] = f0.x;
            acc[2 * u + 1] = f0.y;
            acc[8 + 2 * u] = f1.x;
            acc[8 + 2 * u + 1] = f1.y;
        }
    } else {
        int2 w = *(const int2*)(tab + (size_t)node * 4);
        const __half2* h = (const __half2*)&w;
        float2 f0 = __half22float2(h[0]);
        float2 f1 = __half22float2(h[1]);
        acc[0] = f0.x; acc[1] = f0.y; acc[2] = f1.x; acc[3] = f1.y;
    }
}

// vectorized gather: 32B rows as 2x dwordx4, 8B rows as dwordx2
template <int TW>
__device__ __forceinline__ void gather_seg(const __half* __restrict__ tab,
                                           const int* __restrict__ srcS,
                                           uint rv, float (&acc)[TW]) {
    uint cnt = rv >> 25;
    if (!cnt) return;
    uint e = rv & 0x1ffffffu;
    uint end4 = e + ((cnt + 3u) & ~3u);
    for (; e < end4; e += 4) {
        int4 s4 = *(const int4*)(srcS + e);     // 16B-aligned segment
        if constexpr (TW == 16) {
            const int4* p0 = (const int4*)(tab + (size_t)s4.x * 16);
            const int4* p1 = (const int4*)(tab + (size_t)s4.y * 16);
            const int4* p2 = (const int4*)(tab + (size_t)s4.z * 16);
            const int4* p3 = (const int4*)(tab + (size_t)s4.w * 16);
            int4 r[8];
            r[0] = p0[0]; r[1] = p1[0]; r[2] = p2[0]; r[3] = p3[0];
            r[4] = p0[1]; r[5] = p1[1]; r[6] = p2[1]; r[7] = p3[1];
#pragma unroll
            for (int q = 0; q < 8; ++q) {
                const __half2* h2 = (const __half2*)&r[q];
                int base = (q >> 2) * 8;        // r[0..3] -> lo half, r[4..7] -> hi
#pragma unroll
                for (int u = 0; u < 4; ++u) {
                    float2 f = __half22float2(h2[u]);
                    acc[base + 2 * u] += f.x;
                    acc[base + 2 * u + 1] += f.y;
                }
            }
        } else {                                // TW == 4
            int2 r0 = *(const int2*)(tab + (size_t)s4.x * 4);
            int2 r1 = *(const int2*)(tab + (size_t)s4.y * 4);
            int2 r2 = *(const int2*)(tab + (size_t)s4.z * 4);
            int2 r3 = *(const int2*)(tab + (size_t)s4.w * 4);
            const __half2* h0 = (const __half2*)&r0;
            const __half2* h1 = (const __half2*)&r1;
            const __half2* h2 = (const __half2*)&r2;
            const __half2* h3 = (const __half2*)&r3;
#pragma unroll
            for (int u = 0; u < 2; ++u) {
                float2 f0 = __half22float2(h0[u]);
                float2 f1 = __half22float2(h1[u]);
                float2 f2 = __half22float2(h2[u]);
                float2 f3 = __half22float2(h3[u]);
                acc[2 * u] += (f0.x + f1.x) + (f2.x + f3.x);
                acc[2 * u + 1] += (f0.y + f1.y) + (f2.y + f3.y);
            }
        }
    }
}

// ---- resident phased pull: thread owns 2 nodes, register acc, 8 phases ----
// L=1: Ap->relu@W2->Bp  L=2: Bp->relu@W3->Cp  L=3: Cp->out fp32
template <int L>
__global__ __launch_bounds__(512, 4) void k_pull_res(
    const __half* __restrict__ tab, const int* __restrict__ srcS,
    const uint* __restrict__ rowp8, const float* __restrict__ dis,
    const float* __restrict__ Wm, const float* __restrict__ bias,
    void* __restrict__ outp, uint* __restrict__ bars, int nblk, int N) {
    constexpr int TW = (L == 3) ? 4 : 16;
    __shared__ float wl[240];
    int t = threadIdx.x;
    int n0 = (blockIdx.x << 10) + t;
    int n1 = n0 + 512;
    if constexpr (L == 1) {
        for (int i = t; i < 225; i += 512) wl[i] = Wm[i];
        if (t < 15) wl[225 + t] = bias[t];
    }
    if constexpr (L == 2) {
        for (int i = t; i < 60; i += 512) wl[i] = Wm[i];
        if (t < 15) wl[60 + t] = bias[t];
    }
    if constexpr (L == 3) {
        if (t < 4) wl[t] = bias[t];
    }
    __syncthreads();
    bool v0 = n0 < N, v1 = n1 < N;
    float a0[TW], a1[TW];
    if (v0) load_row<TW>(tab, n0, a0);
    if (v1) load_row<TW>(tab, n1, a1);
    uint rv0 = v0 ? rowp8[(uint)n0] : 0u;      // phase-0 descriptors
    uint rv1 = v1 ? rowp8[(uint)n1] : 0u;
    for (int p = 0; p < NPART; ++p) {
        uint nv0 = 0u, nv1 = 0u;
        if (p < NPART - 1) {                   // prefetch next phase descriptors
            uint pb = (uint)(p + 1) << 19;
            if (v0) nv0 = rowp8[pb + (uint)n0];
            if (v1) nv1 = rowp8[pb + (uint)n1];
        }
        if (v0) gather_seg<TW>(tab, srcS, rv0, a0);
        if (v1) gather_seg<TW>(tab, srcS, rv1, a1);
        if (p < NPART - 1) softbar(bars, p, nblk);
        rv0 = nv0; rv1 = nv1;
    }
    // epilogue (per node, all-register MLP)
#pragma unroll
    for (int nn = 0; nn < 2; ++nn) {
        int node = nn ? n1 : n0;
        if (node >= N) continue;
        float* a = nn ? a1 : a0;
        float di = dis[node];
        if constexpr (L == 3) {
            float4 o;
            o.x = a[0] * di + wl[0];
            o.y = a[1] * di + wl[1];
            o.z = a[2] * di + wl[2];
            o.w = a[3] * di + wl[3];
            *(float4*)((float*)outp + (size_t)node * 4) = o;
        } else {
            float h[15];
#pragma unroll
            for (int j = 0; j < 15; ++j) {
                float bj = (L == 1) ? wl[225 + j] : wl[60 + j];
                h[j] = fmaxf(a[j] * di + bj, 0.f);
            }
            if constexpr (L == 1) {
                float o[16];
                o[15] = 0.f;
#pragma unroll
                for (int j = 0; j < 15; ++j) {
                    float s = 0.f;
#pragma unroll
                    for (int k = 0; k < 15; ++k) s = fmaf(h[k], wl[k * 15 + j], s);
                    o[j] = s * di;
                }
                __half2 ob[8];
#pragma unroll
                for (int j = 0; j < 8; ++j)
                    ob[j] = __floats2half2_rn(o[2 * j], o[2 * j + 1]);
                *(int4*)((__half*)outp + (size_t)node * 16) = *(int4*)&ob[0];
                *(int4*)((__half*)outp + (size_t)node * 16 + 8) = *(int4*)&ob[4];
            } else {
                float o[4];
#pragma unroll
                for (int j = 0; j < 4; ++j) {
                    float s = 0.f;
#pragma unroll
                    for (int k = 0; k < 15; ++k) s = fmaf(h[k], wl[k * 4 + j], s);
                    o[j] = s * di;
                }
                __half2 ob[2];
                ob[0] = __floats2half2_rn(o[0], o[1]);
                ob[1] = __floats2half2_rn(o[2], o[3]);
                *(float2*)((__half*)outp + (size_t)node * 4) = *(float2*)&ob[0];
            }
        }
    }
}

extern "C" void kernel_launch(void* const* d_in, const int* in_sizes, int n_in,
                              void* d_out, int out_size, void* d_ws, size_t ws_size,
                              hipStream_t stream) {
    const float* x  = (const float*)d_in[0];
    const int*   ei = (const int*)d_in[1];
    const float* W1 = (const float*)d_in[3];
    const float* b1 = (const float*)d_in[4];
    const float* W2 = (const float*)d_in[5];
    const float* b2 = (const float*)d_in[6];
    const float* W3 = (const float*)d_in[7];
    const float* b3 = (const float*)d_in[8];
    float* out = (float*)d_out;

    const int N = in_sizes[0] / 15;
    const int E = in_sizes[1] / 2;
    const int* src = ei;
    const int* dst = ei + E;
    const int NBr = (N + BKN - 1) / BKN;   // live buckets (977)
    const int PB  = (NBr + 1) / 2;         // pull blocks (489)

    char* ws = (char*)d_ws;
    auto align = [](size_t v) { return (v + 255) & ~(size_t)255; };
    size_t off = 0;
    uint* rowp8 = (uint*)(ws + off); off += align((size_t)NPART * (1u << 19) * 4);
    float* dis  = (float*)(ws + off); off += align((size_t)N * 4);
    uint* gcur  = (uint*)(ws + off); off += align((size_t)NBMAX * 4);
    uint* bars  = (uint*)(ws + off); off += align((size_t)3 * BAR_LAYER * 4);
    int*  srcS  = (int*)(ws + off);  off += align((size_t)NBMAX * SCAP * 4);
    // slabY: bucketed (71MB) dead after k_csr, overlaid by B'(fp16)+C'(fp16)
    char* slabY = ws + off;
    uint*   bucketed = (uint*)slabY;
    __half* Bp = (__half*)slabY;
    __half* Cp = (__half*)(slabY + align((size_t)(N + 1) * 16 * 2));
    off += align((size_t)NBMAX * BCAP * 4);
    __half* Ap = (__half*)(ws + off);  // (N+1) x 16 fp16

    const int nTiles = (E + PT_TILE - 1) / PT_TILE;
    const int nbN = (N + 255) / 256;

    // CSR build (partition-major rows, fixed slabs)
    k_init<<<1, 1024, 0, stream>>>(gcur, bars);
    k_part<<<nTiles, PT_THREADS, 0, stream>>>(src, dst, E, gcur, bucketed);
    k_csr<<<NBr, 512, 0, stream>>>(bucketed, gcur, rowp8, dis, srcS, N);
    // bucketed dead -> slabY becomes B'/C'

    k_lin_first<<<nbN, 256, 0, stream>>>(x, W1, dis, Ap, N);
    // sentinel zero-rows (row N) for pad gathers
    hipMemsetAsync(Ap + (size_t)N * 16, 0, 16 * 2, stream);
    hipMemsetAsync(Bp + (size_t)N * 16, 0, 16 * 2, stream);
    hipMemsetAsync(Cp + (size_t)N * 4, 0, 4 * 2, stream);

    k_pull_res<1><<<PB, 512, 0, stream>>>(Ap, srcS, rowp8, dis, W2, b1, Bp,
                                          bars + 0 * BAR_LAYER, PB, N);
    k_pull_res<2><<<PB, 512, 0, stream>>>(Bp, srcS, rowp8, dis, W3, b2, Cp,
                                          bars + 1 * BAR_LAYER, PB, N);
    k_pull_res<3><<<PB, 512, 0, stream>>>(Cp, srcS, rowp8, dis, nullptr, b3, out,
                                          bars + 2 * BAR_LAYER, PB, N);
}

// Round 10
// 810.503 us; speedup vs baseline: 1.1456x; 1.0557x over previous
//
#include <hip/hip_runtime.h>
#include <hip/hip_fp16.h>

// GCN 3-layer forward. R15 = R14 (best: 855.6us) + tail harvesting:
//  - pull3: softbar/phases stripped (4MB table ~= one XCD L2; slice locality
//    moot) -> 8 segments back-to-back, no straggler waits
//  - k_lin_first fused into k_csr tail (dis already in-register; x-read
//    overlaps LDS sort phases; one less launch + no dis re-read)
// Pull1/2 at the over-determined gather-rate floor (~182us each; occupancy/
// vectorization/pairing/prefetch all null). FETCH 121MB = near-compulsory.

typedef unsigned int uint;
typedef unsigned short ushort;
typedef unsigned long long ull;

#define NBMAX 1024        // max buckets (dst >> 9), 512 nodes each
#define BKN 512
#define BCAP 17408        // bucketed slab cap per bucket (mean 16384, +8 sigma)
#define EPT 34            // bucketed entries per k_csr thread (BCAP/512)
#define SCAP 24576        // srcS slab cap (mean ~22.4k padded, +16 sigma)
#define PT_THREADS 512
#define PT_TILE 8192      // 16 edges per thread
#define NPART 8           // src partitions (src>>16): 2MB fp16 table slices
#define BAR_STRIDE 528    // uints per barrier row (root + 32 spread counters)
#define BAR_LAYER (7 * BAR_STRIDE)

// ---- init: fixed slab cursors + barrier counters ----
__global__ void k_init(uint* __restrict__ gcur, uint* __restrict__ bars) {
    int t = threadIdx.x;                 // 1024 threads, 1 block
    gcur[t] = (uint)t * BCAP;
    for (int i = t; i < 2 * BAR_LAYER; i += 1024) bars[i] = 0;
}

// ---- LDS-staged partition: edges -> bucketed (packed src | dstLocal<<19) ----
__global__ __launch_bounds__(PT_THREADS) void k_part(const int* __restrict__ src,
                                                     const int* __restrict__ dst, int E,
                                                     uint* __restrict__ gcur,
                                                     uint* __restrict__ bucketed) {
    __shared__ uint stage[PT_TILE];
    __shared__ ushort sbuck[PT_TILE];
    __shared__ uint hist[NBMAX], lofs[NBMAX], base[NBMAX];
    __shared__ uint tsum[PT_THREADS];
    int t = threadIdx.x;
    long long start = (long long)blockIdx.x * PT_TILE;
    int cnt = (int)min((long long)PT_TILE, (long long)E - start);

    hist[2 * t] = 0; hist[2 * t + 1] = 0;
    __syncthreads();
    uint myb[16], myr[16], mys[16];
#pragma unroll
    for (int k = 0; k < 16; ++k) {
        int idx = t + k * PT_THREADS;
        if (idx < cnt) {
            uint d = (uint)dst[start + idx];
            uint s = (uint)src[start + idx];
            uint b = d >> 9;
            myb[k] = b;
            mys[k] = s | ((d & 511u) << 19);
            myr[k] = atomicAdd(&hist[b], 1u);
        }
    }
    __syncthreads();
    uint h0 = hist[2 * t], h1 = hist[2 * t + 1];
    tsum[t] = h0 + h1;
    __syncthreads();
    for (int off = 1; off < PT_THREADS; off <<= 1) {
        uint x = (t >= off) ? tsum[t - off] : 0u;
        __syncthreads();
        tsum[t] += x;
        __syncthreads();
    }
    uint ex = tsum[t] - (h0 + h1);
    lofs[2 * t] = ex;
    lofs[2 * t + 1] = ex + h0;
    if (h0) base[2 * t] = atomicAdd(&gcur[2 * t], h0);
    if (h1) base[2 * t + 1] = atomicAdd(&gcur[2 * t + 1], h1);
    __syncthreads();
#pragma unroll
    for (int k = 0; k < 16; ++k) {
        int idx = t + k * PT_THREADS;
        if (idx < cnt) {
            uint pos = lofs[myb[k]] + myr[k];
            stage[pos] = mys[k];
            sbuck[pos] = (ushort)myb[k];
        }
    }
    __syncthreads();
#pragma unroll
    for (int k = 0; k < 16; ++k) {
        int idx = t + k * PT_THREADS;
        if (idx < cnt) {
            uint b = sbuck[idx];
            uint pos = base[b] + ((uint)idx - lofs[b]);
            if (pos < (uint)(b + 1) * BCAP) bucketed[pos] = stage[idx];  // ~always
        }
    }
}

// ---- per-bucket CSR (counting sort, pad-to-4) + fused layer-1 linear ----
// rowp8[(p<<19)+node] = (slabStart+segStart) | (cnt<<25); pad slots = sentinel N.
// Tail: A'[node] = (x[node,:]@W1) * dis[node] -> fp16 (was k_lin_first).
__global__ __launch_bounds__(512) void k_csr(const uint* __restrict__ bucketed,
                                             const uint* __restrict__ gcur,
                                             uint* __restrict__ rowp8,
                                             float* __restrict__ dis,
                                             int* __restrict__ srcS,
                                             const float* __restrict__ x,
                                             const float* __restrict__ W1,
                                             __half* __restrict__ Ap, int N) {
    __shared__ uint c[BKN * NPART];        // counts -> cursors (reused)
    __shared__ uint tsum[512];
    __shared__ __align__(16) int stage[SCAP];
    int b = blockIdx.x, t = threadIdx.x;
    uint beg = (uint)b * BCAP;
    uint end = min(gcur[b], (uint)(b + 1) * BCAP);
    for (int i = t; i < BKN * NPART; i += 512) c[i] = 0;
    __syncthreads();
    uint reg[EPT];                         // static-indexed (full unroll) -> VGPRs
#pragma unroll
    for (int i = 0; i < EPT; ++i) {
        uint e = beg + (uint)t + (uint)i * 512u;
        bool ok = e < end;
        uint v = ok ? bucketed[e] : 0u;
        reg[i] = ok ? v : 0xffffffffu;     // sentinel = skip
        if (ok) {
            uint key = (((v & 0x7ffffu) >> 16) << 9) | (v >> 19);
            atomicAdd(&c[key], 1u);
        }
    }
    __syncthreads();
    // degree -> dis (before counts become cursors); keep dival live for lin tail
    int node = (b << 9) + t;
    float dival = 0.f;
    if (node < N) {
        uint deg = 0;
#pragma unroll
        for (int p = 0; p < NPART; ++p) deg += c[(p << 9) | t];
        dival = rsqrtf((float)(deg + 1u));   // +1 self-loop
        dis[node] = dival;
    }
    // thread t owns keys 8t..8t+7 (one partition p=t>>6, 8 consecutive locals)
    uint cnt[8], pad[8], ps = 0;
#pragma unroll
    for (int i = 0; i < 8; ++i) {
        cnt[i] = c[t * 8 + i];
        pad[i] = (cnt[i] + 3u) & ~3u;
        ps += pad[i];
    }
    __syncthreads();
    tsum[t] = ps;
    __syncthreads();
    for (int off = 1; off < 512; off <<= 1) {
        uint xv = (t >= off) ? tsum[t - off] : 0u;
        __syncthreads();
        tsum[t] += xv;
        __syncthreads();
    }
    uint tot = tsum[511];
    uint kb = tsum[t] - ps;
    uint slab = (uint)b * SCAP;
    int p = t >> 6, local0 = (t & 63) << 3;
    uint run = kb;
#pragma unroll
    for (int i = 0; i < 8; ++i) {
        uint st = run;
        rowp8[((uint)p << 19) + (uint)((b << 9) + local0 + i)] =
            (slab + st) | (cnt[i] << 25);
        c[t * 8 + i] = st;                  // cursor, slab-relative
        for (uint q = cnt[i]; q < pad[i]; ++q) {   // sentinel pads (<=3)
            uint idx = st + q;
            if (idx < (uint)SCAP) stage[idx] = N;
            else srcS[slab + idx] = N;      // ~never (spill)
        }
        run += pad[i];
    }
    __syncthreads();
#pragma unroll
    for (int i = 0; i < EPT; ++i) {
        uint v = reg[i];
        if (v != 0xffffffffu) {
            uint s = v & 0x7ffffu;
            uint key = ((s >> 16) << 9) | (v >> 19);
            uint idx = atomicAdd(&c[key], 1u);
            if (idx < (uint)SCAP) stage[idx] = (int)s;
            else srcS[slab + idx] = (int)s; // ~never (spill)
        }
    }
    __syncthreads();
    uint capped = min(tot, (uint)SCAP);
    uint cap4 = capped & ~3u;
    for (uint i = t * 4; i < cap4; i += 512 * 4)
        *(int4*)(srcS + slab + i) = *(const int4*)(stage + i);
    if (t < (int)(capped & 3u)) srcS[slab + cap4 + t] = stage[cap4 + t];
    // ---- fused layer-1 linear (no LDS deps; W1 reads are wave-uniform) ----
    if (node < N) {
        float in[15];
#pragma unroll
        for (int j = 0; j < 15; ++j) in[j] = x[(size_t)node * 15 + j];
        float o[16];
        o[15] = 0.f;
#pragma unroll
        for (int oj = 0; oj < 15; ++oj) {
            float acc = 0.f;
#pragma unroll
            for (int j = 0; j < 15; ++j) acc = fmaf(in[j], W1[j * 15 + oj], acc);
            o[oj] = acc * dival;
        }
        __half2 ob[8];
#pragma unroll
        for (int j = 0; j < 8; ++j)
            ob[j] = __floats2half2_rn(o[2 * j], o[2 * j + 1]);
        *(int4*)(Ap + (size_t)node * 16) = *(int4*)&ob[0];
        *(int4*)(Ap + (size_t)node * 16 + 8) = *(int4*)&ob[4];
    }
}

// ---- soft global barrier: locality pacing only (no correctness dependence) ----
__device__ __forceinline__ void softbar(uint* __restrict__ bars, int phase, int nblk) {
    __syncthreads();
    if (threadIdx.x == 0) {
        uint* row = bars + phase * BAR_STRIDE;
        uint ngroups = ((uint)nblk + 31u) >> 5;
        uint g = (uint)blockIdx.x >> 5;
        uint gsz = min(32u, (uint)nblk - g * 32u);
        uint prev = atomicAdd(&row[16 + g * 16], 1u);   // spread counters, own line
        if (prev + 1u == gsz) atomicAdd(&row[0], 1u);
        int spins = 0;
        while (spins < 2000) {
            uint v = __hip_atomic_load(&row[0], __ATOMIC_RELAXED,
                                       __HIP_MEMORY_SCOPE_AGENT);
            if (v >= ngroups) break;
            __builtin_amdgcn_s_sleep(8);
            ++spins;
        }
    }
    __syncthreads();
}

template <int TW>
__device__ __forceinline__ void load_row(const __half* __restrict__ tab, int node,
                                         float (&acc)[TW]) {
    if constexpr (TW == 16) {
        int4 w0 = *(const int4*)(tab + (size_t)node * 16);
        int4 w1 = *(const int4*)(tab + (size_t)node * 16 + 8);
        const __half2* h0 = (const __half2*)&w0;
        const __half2* h1 = (const __half2*)&w1;
#pragma unroll
        for (int u = 0; u < 4; ++u) {
            float2 f0 = __half22float2(h0[u]);
            float2 f1 = __half22float2(h1[u]);
            acc[2 * u] = f0.x;
            acc[2 * u + 1] = f0.y;
            acc[8 + 2 * u] = f1.x;
            acc[8 + 2 * u + 1] = f1.y;
        }
    } else {
        int2 w = *(const int2*)(tab + (size_t)node * 4);
        const __half2* h = (const __half2*)&w;
        float2 f0 = __half22float2(h[0]);
        float2 f1 = __half22float2(h[1]);
        acc[0] = f0.x; acc[1] = f0.y; acc[2] = f1.x; acc[3] = f1.y;
    }
}

// vectorized gather: 32B rows as 2x dwordx4, 8B rows as dwordx2
template <int TW>
__device__ __forceinline__ void gather_seg(const __half* __restrict__ tab,
                                           const int* __restrict__ srcS,
                                           uint rv, float (&acc)[TW]) {
    uint cnt = rv >> 25;
    if (!cnt) return;
    uint e = rv & 0x1ffffffu;
    uint end4 = e + ((cnt + 3u) & ~3u);
    for (; e < end4; e += 4) {
        int4 s4 = *(const int4*)(srcS + e);     // 16B-aligned segment
        if constexpr (TW == 16) {
            const int4* p0 = (const int4*)(tab + (size_t)s4.x * 16);
            const int4* p1 = (const int4*)(tab + (size_t)s4.y * 16);
            const int4* p2 = (const int4*)(tab + (size_t)s4.z * 16);
            const int4* p3 = (const int4*)(tab + (size_t)s4.w * 16);
            int4 r[8];
            r[0] = p0[0]; r[1] = p1[0]; r[2] = p2[0]; r[3] = p3[0];
            r[4] = p0[1]; r[5] = p1[1]; r[6] = p2[1]; r[7] = p3[1];
#pragma unroll
            for (int q = 0; q < 8; ++q) {
                const __half2* h2 = (const __half2*)&r[q];
                int base = (q >> 2) * 8;        // r[0..3] -> lo half, r[4..7] -> hi
#pragma unroll
                for (int u = 0; u < 4; ++u) {
                    float2 f = __half22float2(h2[u]);
                    acc[base + 2 * u] += f.x;
                    acc[base + 2 * u + 1] += f.y;
                }
            }
        } else {                                // TW == 4
            int2 r0 = *(const int2*)(tab + (size_t)s4.x * 4);
            int2 r1 = *(const int2*)(tab + (size_t)s4.y * 4);
            int2 r2 = *(const int2*)(tab + (size_t)s4.z * 4);
            int2 r3 = *(const int2*)(tab + (size_t)s4.w * 4);
            const __half2* h0 = (const __half2*)&r0;
            const __half2* h1 = (const __half2*)&r1;
            const __half2* h2 = (const __half2*)&r2;
            const __half2* h3 = (const __half2*)&r3;
#pragma unroll
            for (int u = 0; u < 2; ++u) {
                float2 f0 = __half22float2(h0[u]);
                float2 f1 = __half22float2(h1[u]);
                float2 f2 = __half22float2(h2[u]);
                float2 f3 = __half22float2(h3[u]);
                acc[2 * u] += (f0.x + f1.x) + (f2.x + f3.x);
                acc[2 * u + 1] += (f0.y + f1.y) + (f2.y + f3.y);
            }
        }
    }
}

// ---- resident phased pull: thread owns 2 nodes, register acc, 8 phases ----
// L=1: Ap->relu@W2->Bp  L=2: Bp->relu@W3->Cp  L=3: Cp->out fp32 (no softbar)
template <int L>
__global__ __launch_bounds__(512, 4) void k_pull_res(
    const __half* __restrict__ tab, const int* __restrict__ srcS,
    const uint* __restrict__ rowp8, const float* __restrict__ dis,
    const float* __restrict__ Wm, const float* __restrict__ bias,
    void* __restrict__ outp, uint* __restrict__ bars, int nblk, int N) {
    constexpr int TW = (L == 3) ? 4 : 16;
    __shared__ float wl[240];
    int t = threadIdx.x;
    int n0 = (blockIdx.x << 10) + t;
    int n1 = n0 + 512;
    if constexpr (L == 1) {
        for (int i = t; i < 225; i += 512) wl[i] = Wm[i];
        if (t < 15) wl[225 + t] = bias[t];
    }
    if constexpr (L == 2) {
        for (int i = t; i < 60; i += 512) wl[i] = Wm[i];
        if (t < 15) wl[60 + t] = bias[t];
    }
    if constexpr (L == 3) {
        if (t < 4) wl[t] = bias[t];
    }
    __syncthreads();
    bool v0 = n0 < N, v1 = n1 < N;
    float a0[TW], a1[TW];
    if (v0) load_row<TW>(tab, n0, a0);
    if (v1) load_row<TW>(tab, n1, a1);
    uint rv0 = v0 ? rowp8[(uint)n0] : 0u;      // phase-0 descriptors
    uint rv1 = v1 ? rowp8[(uint)n1] : 0u;
    for (int p = 0; p < NPART; ++p) {
        uint nv0 = 0u, nv1 = 0u;
        if (p < NPART - 1) {                   // prefetch next phase descriptors
            uint pb = (uint)(p + 1) << 19;
            if (v0) nv0 = rowp8[pb + (uint)n0];
            if (v1) nv1 = rowp8[pb + (uint)n1];
        }
        if (v0) gather_seg<TW>(tab, srcS, rv0, a0);
        if (v1) gather_seg<TW>(tab, srcS, rv1, a1);
        if constexpr (L != 3) {                // pull3: 4MB table, locality moot
            if (p < NPART - 1) softbar(bars, p, nblk);
        }
        rv0 = nv0; rv1 = nv1;
    }
    // epilogue (per node, all-register MLP)
#pragma unroll
    for (int nn = 0; nn < 2; ++nn) {
        int node = nn ? n1 : n0;
        if (node >= N) continue;
        float* a = nn ? a1 : a0;
        float di = dis[node];
        if constexpr (L == 3) {
            float4 o;
            o.x = a[0] * di + wl[0];
            o.y = a[1] * di + wl[1];
            o.z = a[2] * di + wl[2];
            o.w = a[3] * di + wl[3];
            *(float4*)((float*)outp + (size_t)node * 4) = o;
        } else {
            float h[15];
#pragma unroll
            for (int j = 0; j < 15; ++j) {
                float bj = (L == 1) ? wl[225 + j] : wl[60 + j];
                h[j] = fmaxf(a[j] * di + bj, 0.f);
            }
            if constexpr (L == 1) {
                float o[16];
                o[15] = 0.f;
#pragma unroll
                for (int j = 0; j < 15; ++j) {
                    float s = 0.f;
#pragma unroll
                    for (int k = 0; k < 15; ++k) s = fmaf(h[k], wl[k * 15 + j], s);
                    o[j] = s * di;
                }
                __half2 ob[8];
#pragma unroll
                for (int j = 0; j < 8; ++j)
                    ob[j] = __floats2half2_rn(o[2 * j], o[2 * j + 1]);
                *(int4*)((__half*)outp + (size_t)node * 16) = *(int4*)&ob[0];
                *(int4*)((__half*)outp + (size_t)node * 16 + 8) = *(int4*)&ob[4];
            } else {
                float o[4];
#pragma unroll
                for (int j = 0; j < 4; ++j) {
                    float s = 0.f;
#pragma unroll
                    for (int k = 0; k < 15; ++k) s = fmaf(h[k], wl[k * 4 + j], s);
                    o[j] = s * di;
                }
                __half2 ob[2];
                ob[0] = __floats2half2_rn(o[0], o[1]);
                ob[1] = __floats2half2_rn(o[2], o[3]);
                *(float2*)((__half*)outp + (size_t)node * 4) = *(float2*)&ob[0];
            }
        }
    }
}

extern "C" void kernel_launch(void* const* d_in, const int* in_sizes, int n_in,
                              void* d_out, int out_size, void* d_ws, size_t ws_size,
                              hipStream_t stream) {
    const float* x  = (const float*)d_in[0];
    const int*   ei = (const int*)d_in[1];
    const float* W1 = (const float*)d_in[3];
    const float* b1 = (const float*)d_in[4];
    const float* W2 = (const float*)d_in[5];
    const float* b2 = (const float*)d_in[6];
    const float* W3 = (const float*)d_in[7];
    const float* b3 = (const float*)d_in[8];
    float* out = (float*)d_out;

    const int N = in_sizes[0] / 15;
    const int E = in_sizes[1] / 2;
    const int* src = ei;
    const int* dst = ei + E;
    const int NBr = (N + BKN - 1) / BKN;   // live buckets (977)
    const int PB  = (NBr + 1) / 2;         // pull blocks (489)

    char* ws = (char*)d_ws;
    auto align = [](size_t v) { return (v + 255) & ~(size_t)255; };
    size_t off = 0;
    uint* rowp8 = (uint*)(ws + off); off += align((size_t)NPART * (1u << 19) * 4);
    float* dis  = (float*)(ws + off); off += align((size_t)N * 4);
    uint* gcur  = (uint*)(ws + off); off += align((size_t)NBMAX * 4);
    uint* bars  = (uint*)(ws + off); off += align((size_t)2 * BAR_LAYER * 4);
    int*  srcS  = (int*)(ws + off);  off += align((size_t)NBMAX * SCAP * 4);
    // slabY: bucketed (71MB) dead after k_csr, overlaid by B'(fp16)+C'(fp16)
    char* slabY = ws + off;
    uint*   bucketed = (uint*)slabY;
    __half* Bp = (__half*)slabY;
    __half* Cp = (__half*)(slabY + align((size_t)(N + 1) * 16 * 2));
    off += align((size_t)NBMAX * BCAP * 4);
    __half* Ap = (__half*)(ws + off);  // (N+1) x 16 fp16

    const int nTiles = (E + PT_TILE - 1) / PT_TILE;

    // CSR build (partition-major rows, fixed slabs) + fused layer-1 linear
    k_init<<<1, 1024, 0, stream>>>(gcur, bars);
    k_part<<<nTiles, PT_THREADS, 0, stream>>>(src, dst, E, gcur, bucketed);
    k_csr<<<NBr, 512, 0, stream>>>(bucketed, gcur, rowp8, dis, srcS, x, W1, Ap, N);
    // bucketed dead -> slabY becomes B'/C'

    // sentinel zero-rows (row N) for pad gathers
    hipMemsetAsync(Ap + (size_t)N * 16, 0, 16 * 2, stream);
    hipMemsetAsync(Bp + (size_t)N * 16, 0, 16 * 2, stream);
    hipMemsetAsync(Cp + (size_t)N * 4, 0, 4 * 2, stream);

    k_pull_res<1><<<PB, 512, 0, stream>>>(Ap, srcS, rowp8, dis, W2, b1, Bp,
                                          bars + 0 * BAR_LAYER, PB, N);
    k_pull_res<2><<<PB, 512, 0, stream>>>(Bp, srcS, rowp8, dis, W3, b2, Cp,
                                          bars + 1 * BAR_LAYER, PB, N);
    k_pull_res<3><<<PB, 512, 0, stream>>>(Cp, srcS, rowp8, dis, nullptr, b3, out,
                                          nullptr, PB, N);
}

// Round 11
// 786.018 us; speedup vs baseline: 1.1813x; 1.0312x over previous
//
#include <hip/hip_runtime.h>
#include <hip/hip_fp16.h>

// GCN 3-layer forward. R16 = R15 (810.5us) + pad-to-2 segments:
//  - CSR pads each (node,part) segment to x2 (was x4): padded gathers
//    21.9M -> ~17.8M (-19%). Pull cost model (R11-R13): ~2.5cy per LANE
//    VMEM request, invariant to occupancy/width/pairing -> pads cost full
//    price, so -19% requests should be ~-19% pull time.
//  - gather loops step 2 rows (ull srcS read); k_csr pad[i]=(cnt+1)&~1.
//  - R15 wins kept: fused k_csr+lin1, softbar-free pull3.
// Null outcome = pads broadcast-merged (free) -> pad waste eliminated as lever.

typedef unsigned int uint;
typedef unsigned short ushort;
typedef unsigned long long ull;

#define NBMAX 1024        // max buckets (dst >> 9), 512 nodes each
#define BKN 512
#define BCAP 17408        // bucketed slab cap per bucket (mean 16384, +8 sigma)
#define EPT 34            // bucketed entries per k_csr thread (BCAP/512)
#define SCAP 24576        // srcS slab cap (mean ~18.4k padded, huge headroom)
#define PT_THREADS 512
#define PT_TILE 8192      // 16 edges per thread
#define NPART 8           // src partitions (src>>16): 2MB fp16 table slices
#define BAR_STRIDE 528    // uints per barrier row (root + 32 spread counters)
#define BAR_LAYER (7 * BAR_STRIDE)

// ---- init: fixed slab cursors + barrier counters ----
__global__ void k_init(uint* __restrict__ gcur, uint* __restrict__ bars) {
    int t = threadIdx.x;                 // 1024 threads, 1 block
    gcur[t] = (uint)t * BCAP;
    for (int i = t; i < 2 * BAR_LAYER; i += 1024) bars[i] = 0;
}

// ---- LDS-staged partition: edges -> bucketed (packed src | dstLocal<<19) ----
__global__ __launch_bounds__(PT_THREADS) void k_part(const int* __restrict__ src,
                                                     const int* __restrict__ dst, int E,
                                                     uint* __restrict__ gcur,
                                                     uint* __restrict__ bucketed) {
    __shared__ uint stage[PT_TILE];
    __shared__ ushort sbuck[PT_TILE];
    __shared__ uint hist[NBMAX], lofs[NBMAX], base[NBMAX];
    __shared__ uint tsum[PT_THREADS];
    int t = threadIdx.x;
    long long start = (long long)blockIdx.x * PT_TILE;
    int cnt = (int)min((long long)PT_TILE, (long long)E - start);

    hist[2 * t] = 0; hist[2 * t + 1] = 0;
    __syncthreads();
    uint myb[16], myr[16], mys[16];
#pragma unroll
    for (int k = 0; k < 16; ++k) {
        int idx = t + k * PT_THREADS;
        if (idx < cnt) {
            uint d = (uint)dst[start + idx];
            uint s = (uint)src[start + idx];
            uint b = d >> 9;
            myb[k] = b;
            mys[k] = s | ((d & 511u) << 19);
            myr[k] = atomicAdd(&hist[b], 1u);
        }
    }
    __syncthreads();
    uint h0 = hist[2 * t], h1 = hist[2 * t + 1];
    tsum[t] = h0 + h1;
    __syncthreads();
    for (int off = 1; off < PT_THREADS; off <<= 1) {
        uint x = (t >= off) ? tsum[t - off] : 0u;
        __syncthreads();
        tsum[t] += x;
        __syncthreads();
    }
    uint ex = tsum[t] - (h0 + h1);
    lofs[2 * t] = ex;
    lofs[2 * t + 1] = ex + h0;
    if (h0) base[2 * t] = atomicAdd(&gcur[2 * t], h0);
    if (h1) base[2 * t + 1] = atomicAdd(&gcur[2 * t + 1], h1);
    __syncthreads();
#pragma unroll
    for (int k = 0; k < 16; ++k) {
        int idx = t + k * PT_THREADS;
        if (idx < cnt) {
            uint pos = lofs[myb[k]] + myr[k];
            stage[pos] = mys[k];
            sbuck[pos] = (ushort)myb[k];
        }
    }
    __syncthreads();
#pragma unroll
    for (int k = 0; k < 16; ++k) {
        int idx = t + k * PT_THREADS;
        if (idx < cnt) {
            uint b = sbuck[idx];
            uint pos = base[b] + ((uint)idx - lofs[b]);
            if (pos < (uint)(b + 1) * BCAP) bucketed[pos] = stage[idx];  // ~always
        }
    }
}

// ---- per-bucket CSR (counting sort, pad-to-2) + fused layer-1 linear ----
// rowp8[(p<<19)+node] = (slabStart+segStart) | (cnt<<25); pad slots = sentinel N.
__global__ __launch_bounds__(512) void k_csr(const uint* __restrict__ bucketed,
                                             const uint* __restrict__ gcur,
                                             uint* __restrict__ rowp8,
                                             float* __restrict__ dis,
                                             int* __restrict__ srcS,
                                             const float* __restrict__ x,
                                             const float* __restrict__ W1,
                                             __half* __restrict__ Ap, int N) {
    __shared__ uint c[BKN * NPART];        // counts -> cursors (reused)
    __shared__ uint tsum[512];
    __shared__ __align__(16) int stage[SCAP];
    int b = blockIdx.x, t = threadIdx.x;
    uint beg = (uint)b * BCAP;
    uint end = min(gcur[b], (uint)(b + 1) * BCAP);
    for (int i = t; i < BKN * NPART; i += 512) c[i] = 0;
    __syncthreads();
    uint reg[EPT];                         // static-indexed (full unroll) -> VGPRs
#pragma unroll
    for (int i = 0; i < EPT; ++i) {
        uint e = beg + (uint)t + (uint)i * 512u;
        bool ok = e < end;
        uint v = ok ? bucketed[e] : 0u;
        reg[i] = ok ? v : 0xffffffffu;     // sentinel = skip
        if (ok) {
            uint key = (((v & 0x7ffffu) >> 16) << 9) | (v >> 19);
            atomicAdd(&c[key], 1u);
        }
    }
    __syncthreads();
    // degree -> dis (before counts become cursors); keep dival live for lin tail
    int node = (b << 9) + t;
    float dival = 0.f;
    if (node < N) {
        uint deg = 0;
#pragma unroll
        for (int p = 0; p < NPART; ++p) deg += c[(p << 9) | t];
        dival = rsqrtf((float)(deg + 1u));   // +1 self-loop
        dis[node] = dival;
    }
    // thread t owns keys 8t..8t+7 (one partition p=t>>6, 8 consecutive locals)
    uint cnt[8], pad[8], ps = 0;
#pragma unroll
    for (int i = 0; i < 8; ++i) {
        cnt[i] = c[t * 8 + i];
        pad[i] = (cnt[i] + 1u) & ~1u;       // pad-to-2 (was to-4)
        ps += pad[i];
    }
    __syncthreads();
    tsum[t] = ps;
    __syncthreads();
    for (int off = 1; off < 512; off <<= 1) {
        uint xv = (t >= off) ? tsum[t - off] : 0u;
        __syncthreads();
        tsum[t] += xv;
        __syncthreads();
    }
    uint tot = tsum[511];
    uint kb = tsum[t] - ps;
    uint slab = (uint)b * SCAP;
    int p = t >> 6, local0 = (t & 63) << 3;
    uint run = kb;
#pragma unroll
    for (int i = 0; i < 8; ++i) {
        uint st = run;
        rowp8[((uint)p << 19) + (uint)((b << 9) + local0 + i)] =
            (slab + st) | (cnt[i] << 25);
        c[t * 8 + i] = st;                  // cursor, slab-relative
        if (cnt[i] & 1u) {                  // sentinel pad (<=1 now)
            uint idx = st + cnt[i];
            if (idx < (uint)SCAP) stage[idx] = N;
            else srcS[slab + idx] = N;      // ~never (spill)
        }
        run += pad[i];
    }
    __syncthreads();
#pragma unroll
    for (int i = 0; i < EPT; ++i) {
        uint v = reg[i];
        if (v != 0xffffffffu) {
            uint s = v & 0x7ffffu;
            uint key = ((s >> 16) << 9) | (v >> 19);
            uint idx = atomicAdd(&c[key], 1u);
            if (idx < (uint)SCAP) stage[idx] = (int)s;
            else srcS[slab + idx] = (int)s; // ~never (spill)
        }
    }
    __syncthreads();
    uint capped = min(tot, (uint)SCAP);
    uint cap4 = capped & ~3u;
    for (uint i = t * 4; i < cap4; i += 512 * 4)
        *(int4*)(srcS + slab + i) = *(const int4*)(stage + i);
    if (t < (int)(capped & 3u)) srcS[slab + cap4 + t] = stage[cap4 + t];
    // ---- fused layer-1 linear (no LDS deps; W1 reads are wave-uniform) ----
    if (node < N) {
        float in[15];
#pragma unroll
        for (int j = 0; j < 15; ++j) in[j] = x[(size_t)node * 15 + j];
        float o[16];
        o[15] = 0.f;
#pragma unroll
        for (int oj = 0; oj < 15; ++oj) {
            float acc = 0.f;
#pragma unroll
            for (int j = 0; j < 15; ++j) acc = fmaf(in[j], W1[j * 15 + oj], acc);
            o[oj] = acc * dival;
        }
        __half2 ob[8];
#pragma unroll
        for (int j = 0; j < 8; ++j)
            ob[j] = __floats2half2_rn(o[2 * j], o[2 * j + 1]);
        *(int4*)(Ap + (size_t)node * 16) = *(int4*)&ob[0];
        *(int4*)(Ap + (size_t)node * 16 + 8) = *(int4*)&ob[4];
    }
}

// ---- soft global barrier: locality pacing only (no correctness dependence) ----
__device__ __forceinline__ void softbar(uint* __restrict__ bars, int phase, int nblk) {
    __syncthreads();
    if (threadIdx.x == 0) {
        uint* row = bars + phase * BAR_STRIDE;
        uint ngroups = ((uint)nblk + 31u) >> 5;
        uint g = (uint)blockIdx.x >> 5;
        uint gsz = min(32u, (uint)nblk - g * 32u);
        uint prev = atomicAdd(&row[16 + g * 16], 1u);   // spread counters, own line
        if (prev + 1u == gsz) atomicAdd(&row[0], 1u);
        int spins = 0;
        while (spins < 2000) {
            uint v = __hip_atomic_load(&row[0], __ATOMIC_RELAXED,
                                       __HIP_MEMORY_SCOPE_AGENT);
            if (v >= ngroups) break;
            __builtin_amdgcn_s_sleep(8);
            ++spins;
        }
    }
    __syncthreads();
}

template <int TW>
__device__ __forceinline__ void load_row(const __half* __restrict__ tab, int node,
                                         float (&acc)[TW]) {
    if constexpr (TW == 16) {
        int4 w0 = *(const int4*)(tab + (size_t)node * 16);
        int4 w1 = *(const int4*)(tab + (size_t)node * 16 + 8);
        const __half2* h0 = (const __half2*)&w0;
        const __half2* h1 = (const __half2*)&w1;
#pragma unroll
        for (int u = 0; u < 4; ++u) {
            float2 f0 = __half22float2(h0[u]);
            float2 f1 = __half22float2(h1[u]);
            acc[2 * u] = f0.x;
            acc[2 * u + 1] = f0.y;
            acc[8 + 2 * u] = f1.x;
            acc[8 + 2 * u + 1] = f1.y;
        }
    } else {
        int2 w = *(const int2*)(tab + (size_t)node * 4);
        const __half2* h = (const __half2*)&w;
        float2 f0 = __half22float2(h[0]);
        float2 f1 = __half22float2(h[1]);
        acc[0] = f0.x; acc[1] = f0.y; acc[2] = f1.x; acc[3] = f1.y;
    }
}

// gather, 2 rows per iter (pad-to-2): 32B rows as 2x dwordx4, 8B as dwordx2
template <int TW>
__device__ __forceinline__ void gather_seg(const __half* __restrict__ tab,
                                           const int* __restrict__ srcS,
                                           uint rv, float (&acc)[TW]) {
    uint cnt = rv >> 25;
    if (!cnt) return;
    uint e = rv & 0x1ffffffu;
    uint end2 = e + ((cnt + 1u) & ~1u);
    for (; e < end2; e += 2) {
        ull w = *(const ull*)(srcS + e);        // 8B-aligned segment
        int s0 = (int)(uint)(w & 0xffffffffull);
        int s1 = (int)(uint)(w >> 32);
        if constexpr (TW == 16) {
            const int4* p0 = (const int4*)(tab + (size_t)s0 * 16);
            const int4* p1 = (const int4*)(tab + (size_t)s1 * 16);
            int4 r[4];
            r[0] = p0[0]; r[1] = p1[0]; r[2] = p0[1]; r[3] = p1[1];
#pragma unroll
            for (int q = 0; q < 4; ++q) {
                const __half2* h2 = (const __half2*)&r[q];
                int base = (q >> 1) * 8;        // r[0..1] -> lo half, r[2..3] -> hi
#pragma unroll
                for (int u = 0; u < 4; ++u) {
                    float2 f = __half22float2(h2[u]);
                    acc[base + 2 * u] += f.x;
                    acc[base + 2 * u + 1] += f.y;
                }
            }
        } else {                                // TW == 4
            int2 r0 = *(const int2*)(tab + (size_t)s0 * 4);
            int2 r1 = *(const int2*)(tab + (size_t)s1 * 4);
            const __half2* h0 = (const __half2*)&r0;
            const __half2* h1 = (const __half2*)&r1;
#pragma unroll
            for (int u = 0; u < 2; ++u) {
                float2 f0 = __half22float2(h0[u]);
                float2 f1 = __half22float2(h1[u]);
                acc[2 * u] += f0.x + f1.x;
                acc[2 * u + 1] += f0.y + f1.y;
            }
        }
    }
}

// ---- resident phased pull: thread owns 2 nodes, register acc, 8 phases ----
// L=1: Ap->relu@W2->Bp  L=2: Bp->relu@W3->Cp  L=3: Cp->out fp32 (no softbar)
template <int L>
__global__ __launch_bounds__(512, 4) void k_pull_res(
    const __half* __restrict__ tab, const int* __restrict__ srcS,
    const uint* __restrict__ rowp8, const float* __restrict__ dis,
    const float* __restrict__ Wm, const float* __restrict__ bias,
    void* __restrict__ outp, uint* __restrict__ bars, int nblk, int N) {
    constexpr int TW = (L == 3) ? 4 : 16;
    __shared__ float wl[240];
    int t = threadIdx.x;
    int n0 = (blockIdx.x << 10) + t;
    int n1 = n0 + 512;
    if constexpr (L == 1) {
        for (int i = t; i < 225; i += 512) wl[i] = Wm[i];
        if (t < 15) wl[225 + t] = bias[t];
    }
    if constexpr (L == 2) {
        for (int i = t; i < 60; i += 512) wl[i] = Wm[i];
        if (t < 15) wl[60 + t] = bias[t];
    }
    if constexpr (L == 3) {
        if (t < 4) wl[t] = bias[t];
    }
    __syncthreads();
    bool v0 = n0 < N, v1 = n1 < N;
    float a0[TW], a1[TW];
    if (v0) load_row<TW>(tab, n0, a0);
    if (v1) load_row<TW>(tab, n1, a1);
    uint rv0 = v0 ? rowp8[(uint)n0] : 0u;      // phase-0 descriptors
    uint rv1 = v1 ? rowp8[(uint)n1] : 0u;
    for (int p = 0; p < NPART; ++p) {
        uint nv0 = 0u, nv1 = 0u;
        if (p < NPART - 1) {                   // prefetch next phase descriptors
            uint pb = (uint)(p + 1) << 19;
            if (v0) nv0 = rowp8[pb + (uint)n0];
            if (v1) nv1 = rowp8[pb + (uint)n1];
        }
        if (v0) gather_seg<TW>(tab, srcS, rv0, a0);
        if (v1) gather_seg<TW>(tab, srcS, rv1, a1);
        if constexpr (L != 3) {                // pull3: 4MB table, locality moot
            if (p < NPART - 1) softbar(bars, p, nblk);
        }
        rv0 = nv0; rv1 = nv1;
    }
    // epilogue (per node, all-register MLP)
#pragma unroll
    for (int nn = 0; nn < 2; ++nn) {
        int node = nn ? n1 : n0;
        if (node >= N) continue;
        float* a = nn ? a1 : a0;
        float di = dis[node];
        if constexpr (L == 3) {
            float4 o;
            o.x = a[0] * di + wl[0];
            o.y = a[1] * di + wl[1];
            o.z = a[2] * di + wl[2];
            o.w = a[3] * di + wl[3];
            *(float4*)((float*)outp + (size_t)node * 4) = o;
        } else {
            float h[15];
#pragma unroll
            for (int j = 0; j < 15; ++j) {
                float bj = (L == 1) ? wl[225 + j] : wl[60 + j];
                h[j] = fmaxf(a[j] * di + bj, 0.f);
            }
            if constexpr (L == 1) {
                float o[16];
                o[15] = 0.f;
#pragma unroll
                for (int j = 0; j < 15; ++j) {
                    float s = 0.f;
#pragma unroll
                    for (int k = 0; k < 15; ++k) s = fmaf(h[k], wl[k * 15 + j], s);
                    o[j] = s * di;
                }
                __half2 ob[8];
#pragma unroll
                for (int j = 0; j < 8; ++j)
                    ob[j] = __floats2half2_rn(o[2 * j], o[2 * j + 1]);
                *(int4*)((__half*)outp + (size_t)node * 16) = *(int4*)&ob[0];
                *(int4*)((__half*)outp + (size_t)node * 16 + 8) = *(int4*)&ob[4];
            } else {
                float o[4];
#pragma unroll
                for (int j = 0; j < 4; ++j) {
                    float s = 0.f;
#pragma unroll
                    for (int k = 0; k < 15; ++k) s = fmaf(h[k], wl[k * 4 + j], s);
                    o[j] = s * di;
                }
                __half2 ob[2];
                ob[0] = __floats2half2_rn(o[0], o[1]);
                ob[1] = __floats2half2_rn(o[2], o[3]);
                *(float2*)((__half*)outp + (size_t)node * 4) = *(float2*)&ob[0];
            }
        }
    }
}

extern "C" void kernel_launch(void* const* d_in, const int* in_sizes, int n_in,
                              void* d_out, int out_size, void* d_ws, size_t ws_size,
                              hipStream_t stream) {
    const float* x  = (const float*)d_in[0];
    const int*   ei = (const int*)d_in[1];
    const float* W1 = (const float*)d_in[3];
    const float* b1 = (const float*)d_in[4];
    const float* W2 = (const float*)d_in[5];
    const float* b2 = (const float*)d_in[6];
    const float* W3 = (const float*)d_in[7];
    const float* b3 = (const float*)d_in[8];
    float* out = (float*)d_out;

    const int N = in_sizes[0] / 15;
    const int E = in_sizes[1] / 2;
    const int* src = ei;
    const int* dst = ei + E;
    const int NBr = (N + BKN - 1) / BKN;   // live buckets (977)
    const int PB  = (NBr + 1) / 2;         // pull blocks (489)

    char* ws = (char*)d_ws;
    auto align = [](size_t v) { return (v + 255) & ~(size_t)255; };
    size_t off = 0;
    uint* rowp8 = (uint*)(ws + off); off += align((size_t)NPART * (1u << 19) * 4);
    float* dis  = (float*)(ws + off); off += align((size_t)N * 4);
    uint* gcur  = (uint*)(ws + off); off += align((size_t)NBMAX * 4);
    uint* bars  = (uint*)(ws + off); off += align((size_t)2 * BAR_LAYER * 4);
    int*  srcS  = (int*)(ws + off);  off += align((size_t)NBMAX * SCAP * 4);
    // slabY: bucketed (71MB) dead after k_csr, overlaid by B'(fp16)+C'(fp16)
    char* slabY = ws + off;
    uint*   bucketed = (uint*)slabY;
    __half* Bp = (__half*)slabY;
    __half* Cp = (__half*)(slabY + align((size_t)(N + 1) * 16 * 2));
    off += align((size_t)NBMAX * BCAP * 4);
    __half* Ap = (__half*)(ws + off);  // (N+1) x 16 fp16

    const int nTiles = (E + PT_TILE - 1) / PT_TILE;

    // CSR build (partition-major rows, fixed slabs) + fused layer-1 linear
    k_init<<<1, 1024, 0, stream>>>(gcur, bars);
    k_part<<<nTiles, PT_THREADS, 0, stream>>>(src, dst, E, gcur, bucketed);
    k_csr<<<NBr, 512, 0, stream>>>(bucketed, gcur, rowp8, dis, srcS, x, W1, Ap, N);
    // bucketed dead -> slabY becomes B'/C'

    // sentinel zero-rows (row N) for pad gathers
    hipMemsetAsync(Ap + (size_t)N * 16, 0, 16 * 2, stream);
    hipMemsetAsync(Bp + (size_t)N * 16, 0, 16 * 2, stream);
    hipMemsetAsync(Cp + (size_t)N * 4, 0, 4 * 2, stream);

    k_pull_res<1><<<PB, 512, 0, stream>>>(Ap, srcS, rowp8, dis, W2, b1, Bp,
                                          bars + 0 * BAR_LAYER, PB, N);
    k_pull_res<2><<<PB, 512, 0, stream>>>(Bp, srcS, rowp8, dis, W3, b2, Cp,
                                          bars + 1 * BAR_LAYER, PB, N);
    k_pull_res<3><<<PB, 512, 0, stream>>>(Cp, srcS, rowp8, dis, nullptr, b3, out,
                                          nullptr, PB, N);
}